// Round 19
// baseline (163.825 us; speedup 1.0000x reference)
//
#include <hip/hip_runtime.h>
#include <hip/hip_bf16.h>
#include <hip/hip_fp16.h>
#include <math.h>

// ---------------- problem constants ----------------
#define NN      8192
#define VV      8
#define PP      1024      // N / V
#define MM      2048
#define HE_DIM  1024
#define ST_DIM  512
#define D_OUT   256
#define K_HG    5
#define RADIUS  150.0f
#define TEMP    0.07f
#define EPSF    1e-12f

#define POOL_CHUNK 4
#define HE_NCH  (PP / POOL_CHUNK)   // 256
#define ST_NCH  (MM / POOL_CHUNK)   // 512
#define DEG_CAP 96                  // max node in-degree (KNN in-degree max ~20)

// grouped-GEMM block ranges
#define HE_TRI   36                 // 8x8 upper triangle
#define ST_TRI   136                // 16x16 upper triangle
#define NB_HE    (VV * HE_TRI)      // 288
#define NB_ST    ST_TRI             // 136
#define NB_PH    ((NN / 128) * (D_OUT / 128))   // 128
#define NB_PS    ((MM / 128) * (D_OUT / 128))   // 32
#define NB_ALL   (NB_HE + NB_ST + NB_PH + NB_PS) // 584 = 8 * 73

#define NPREP   (NN + MM + 2 * D_OUT)   // rows handled by prep; +VV extra blocks

typedef __bf16 bf16x8 __attribute__((ext_vector_type(8)));
typedef float  f32x4  __attribute__((ext_vector_type(4)));
typedef unsigned short ushort_t;

typedef __attribute__((address_space(1))) void gvoid;
typedef __attribute__((address_space(3))) void svoid;
#define GLOAD16(g, l) __builtin_amdgcn_global_load_lds((gvoid*)(g), (svoid*)(l), 16, 0, 0)
#define FENCE() asm volatile("" ::: "memory")

__device__ __forceinline__ ushort_t f2bf(float x) {
    unsigned int b = __float_as_uint(x);
    return (ushort_t)((b + 0x7fffu + ((b >> 16) & 1u)) >> 16);   // RNE
}
__device__ __forceinline__ float bf2f(ushort_t h) {
    return __uint_as_float(((unsigned int)h) << 16);
}
__device__ __forceinline__ ushort_t f2h(float x) {
    return __half_as_ushort(__float2half_rn(x));
}

// ---------------- fused: split + rownorm + (centers/mask/zero in tail blocks) ----------------
__global__ __launch_bounds__(256) void prep_kernel(
    const float* __restrict__ F, const float* __restrict__ E,
    const float* __restrict__ Whe, const float* __restrict__ Wst,
    const float* __restrict__ T, const float* __restrict__ S,
    ushort_t* __restrict__ Fs, ushort_t* __restrict__ Es,
    ushort_t* __restrict__ Whes, ushort_t* __restrict__ Wsts,
    float* __restrict__ rnF, float* __restrict__ rnE,
    int* __restrict__ mask, int* __restrict__ maskcnt,
    int* __restrict__ zeroPtr, int nZeroInts)
{
    int b = blockIdx.x;
    if (b >= NPREP) {
        int v = b - NPREP;
        int per = (nZeroInts + VV - 1) / VV;
        for (int i = threadIdx.x; i < per; i += 256) {
            int idx = v * per + i;
            if (idx < nZeroInts) zeroPtr[idx] = 0;
        }
        float sx = 0.0f, sy = 0.0f;
        for (int i = threadIdx.x; i < PP; i += 256) {
            sx += T[(long)(v * PP + i) * 2 + 0];
            sy += T[(long)(v * PP + i) * 2 + 1];
        }
        __shared__ float rx[256], ry[256];
        __shared__ int   rc[256];
        rx[threadIdx.x] = sx; ry[threadIdx.x] = sy; __syncthreads();
        for (int o = 128; o > 0; o >>= 1) {
            if (threadIdx.x < o) { rx[threadIdx.x] += rx[threadIdx.x + o]; ry[threadIdx.x] += ry[threadIdx.x + o]; }
            __syncthreads();
        }
        float cx = rx[0] / (float)PP, cy = ry[0] / (float)PP;
        __syncthreads();
        int cnt = 0;
        for (int m = threadIdx.x; m < MM; m += 256) {
            float dx = cx - S[m * 2 + 0];
            float dy = cy - S[m * 2 + 1];
            int in = (sqrtf(dx * dx + dy * dy) < RADIUS) ? 1 : 0;
            mask[v * MM + m] = in;
            cnt += in;
        }
        rc[threadIdx.x] = cnt; __syncthreads();
        for (int o = 128; o > 0; o >>= 1) {
            if (threadIdx.x < o) rc[threadIdx.x] += rc[threadIdx.x + o];
            __syncthreads();
        }
        if (threadIdx.x == 0) maskcnt[v] = rc[0];
        return;
    }
    const float* src; ushort_t* dst; float* rn; int K; long row;
    if (b < NN)                    { src = F;   dst = Fs;   rn = rnF;    K = HE_DIM; row = b; }
    else if (b < NN + MM)          { src = E;   dst = Es;   rn = rnE;    K = ST_DIM; row = b - NN; }
    else if (b < NN + MM + D_OUT)  { src = Whe; dst = Whes; rn = nullptr; K = HE_DIM; row = b - NN - MM; }
    else                           { src = Wst; dst = Wsts; rn = nullptr; K = ST_DIM; row = b - NN - MM - D_OUT; }
    const float4* srow = (const float4*)(src + row * (long)K);
    ushort_t* drow = dst + row * 2L * K;
    float s = 0.0f;
    for (int j4 = threadIdx.x; j4 < (K >> 2); j4 += 256) {
        float4 x = srow[j4];
        float xs[4] = {x.x, x.y, x.z, x.w};
        ushort_t hs[4], ls[4];
        #pragma unroll
        for (int t = 0; t < 4; ++t) {
            hs[t] = f2bf(xs[t]);
            ls[t] = f2bf(xs[t] - bf2f(hs[t]));    // lo residual
            s += xs[t] * xs[t];
        }
        *(ushort4*)(drow + j4 * 4)     = make_ushort4(hs[0], hs[1], hs[2], hs[3]);
        *(ushort4*)(drow + K + j4 * 4) = make_ushort4(ls[0], ls[1], ls[2], ls[3]);
    }
    if (rn) {
        __shared__ float red[256];
        red[threadIdx.x] = s; __syncthreads();
        for (int o = 128; o > 0; o >>= 1) {
            if (threadIdx.x < o) red[threadIdx.x] += red[threadIdx.x + o];
            __syncthreads();
        }
        if (threadIdx.x == 0) rn[row] = 1.0f / fmaxf(sqrtf(red[0]), EPSF);
    }
}

// ---------------- grouped split-bf16 MFMA GEMM, 48 KB LDS (3 blocks/CU) ----------------
// nseg=1 (HE Gram):  3-buf {AH,BH} 16 KB, depth-2, vmcnt(8)
// nseg=2 (ST Gram):  2-buf {AH,AL,BH} 24 KB, depth-1, vmcnt(6)
// nseg=3 (proj):     1-buf {AH,AL,BH,BL} 32 KB, depth-0, vmcnt(0)
__global__ __launch_bounds__(256) void gemm_grouped(
    const ushort_t* __restrict__ Fs, const ushort_t* __restrict__ Es,
    const ushort_t* __restrict__ Whes, const ushort_t* __restrict__ Wsts,
    ushort_t* __restrict__ he_sim, ushort_t* __restrict__ st_sim,
    float* __restrict__ Xw_he, float* __restrict__ Xw_st,
    const float* __restrict__ rnF, const float* __restrict__ rnE)
{
    // Balanced XCD map: XCD k owns region k's 36 HE tiles; round-robin rest.
    int bid = blockIdx.x;
    int xcd = bid & 7, j = bid >> 3;    // 584 = 8*73, bijective
    int id = (j < HE_TRI) ? (xcd * HE_TRI + j)
                          : (NB_HE + (j - HE_TRI) * 8 + xcd);

    const ushort_t *A, *B; ushort_t *Ch = nullptr; float *Cf = nullptr;
    const float *rA = nullptr, *rB = nullptr;
    int K, Nn, bm, bn, sym, nseg;
    if (id < NB_HE) {
        int z = id / HE_TRI, t = id - z * HE_TRI;
        int i = 0;
        while (t >= 8 - i) { t -= 8 - i; ++i; }
        bm = i * 128; bn = (i + t) * 128;
        A = B = Fs + (long)z * PP * 2 * HE_DIM;
        Ch = he_sim + (long)z * PP * PP;
        rA = rB = rnF + z * PP;
        K = HE_DIM; Nn = PP; sym = 1; nseg = 1;
    } else if (id < NB_HE + NB_ST) {
        int t = id - NB_HE;
        int i = 0;
        while (t >= 16 - i) { t -= 16 - i; ++i; }
        bm = i * 128; bn = (i + t) * 128;
        A = B = Es; Ch = st_sim; rA = rB = rnE;
        K = ST_DIM; Nn = MM; sym = 1; nseg = 2;
    } else if (id < NB_HE + NB_ST + NB_PH) {
        int t = id - (NB_HE + NB_ST);
        bm = (t >> 1) * 128; bn = (t & 1) * 128;
        A = Fs; B = Whes; Cf = Xw_he;
        K = HE_DIM; Nn = D_OUT; sym = 0; nseg = 3;
    } else {
        int t = id - (NB_HE + NB_ST + NB_PH);
        bm = (t >> 1) * 128; bn = (t & 1) * 128;
        A = Es; B = Wsts; Cf = Xw_st;
        K = ST_DIM; Nn = D_OUT; sym = 0; nseg = 3;
    }

    __shared__ ushort_t sm[24576];   // 48 KB -> 3 blocks/CU
    char* const smb = (char*)&sm[0];
    const int tid  = threadIdx.x;
    const int lane = tid & 63, wave = tid >> 6;
    const int wr = wave >> 1, wc = wave & 1;
    const int fr = lane & 15, fg = lane >> 4;

    const long lda = 2L * K;
    const int srow = wave * 16 + (lane >> 2);
    const int scol = (((lane & 3) ^ ((srow >> 1) & 3)) * 8);  // pre-swizzled src col

    f32x4 acc[4][4] = {};

    auto roA = [&](int m) { int row = wr * 64 + m * 16 + fr;
                            return row * 64 + ((fg ^ ((row >> 1) & 3)) * 16); };
    auto roB = [&](int n) { int row = wc * 64 + n * 16 + fr;
                            return row * 64 + ((fg ^ ((row >> 1) & 3)) * 16); };

    if (nseg == 1) {
        // ---- 3-buffer depth-2: {AH, BH} = 16 KB/buf ----
        auto STG = [&](int kk, int b) {
            const ushort_t* ga = A + (long)(bm + srow) * lda + kk + scol;
            const ushort_t* gb = B + (long)(bn + srow) * lda + kk + scol;
            char* AH = smb + b * 16384 + wave * 1024;
            char* BH = smb + b * 16384 + 8192 + wave * 1024;
            GLOAD16(ga, AH); GLOAD16(ga + 64 * lda, AH + 4096);
            GLOAD16(gb, BH); GLOAD16(gb + 64 * lda, BH + 4096);
        };
        STG(0, 0); STG(32, 1);
        int buf = 0;
        for (int kk = 0; kk < K; kk += 32) {
            if (kk + 64 < K) {
                STG(kk + 64, buf == 0 ? 2 : buf - 1);
                asm volatile("s_waitcnt vmcnt(8)" ::: "memory");
            } else if (kk + 32 < K) {
                asm volatile("s_waitcnt vmcnt(4)" ::: "memory");
            } else {
                asm volatile("s_waitcnt vmcnt(0)" ::: "memory");
            }
            FENCE(); __builtin_amdgcn_s_barrier(); FENCE();
            const char* ab = smb + buf * 16384;
            bf16x8 ah[4], bh[4];
            #pragma unroll
            for (int m = 0; m < 4; ++m) ah[m] = *(const bf16x8*)(ab + roA(m));
            #pragma unroll
            for (int n = 0; n < 4; ++n) bh[n] = *(const bf16x8*)(ab + 8192 + roB(n));
            #pragma unroll
            for (int m = 0; m < 4; ++m)
                #pragma unroll
                for (int n = 0; n < 4; ++n)
                    acc[m][n] = __builtin_amdgcn_mfma_f32_16x16x32_bf16(ah[m], bh[n], acc[m][n], 0, 0, 0);
            FENCE(); __builtin_amdgcn_s_barrier(); FENCE();
            buf = (buf == 2) ? 0 : buf + 1;
        }
    } else if (nseg == 2) {
        // ---- 2-buffer depth-1: {AH, AL, BH} = 24 KB/buf ----
        auto STG = [&](int kk, int b) {
            const ushort_t* ga = A + (long)(bm + srow) * lda + kk + scol;
            const ushort_t* gb = B + (long)(bn + srow) * lda + kk + scol;
            char* AH = smb + b * 24576 + wave * 1024;
            char* AL = AH + 8192;
            char* BH = AH + 16384;
            GLOAD16(ga,     AH); GLOAD16(ga + 64 * lda,     AH + 4096);
            GLOAD16(ga + K, AL); GLOAD16(ga + K + 64 * lda, AL + 4096);
            GLOAD16(gb,     BH); GLOAD16(gb + 64 * lda,     BH + 4096);
        };
        STG(0, 0);
        int buf = 0;
        for (int kk = 0; kk < K; kk += 32) {
            if (kk + 32 < K) {
                STG(kk + 32, buf ^ 1);
                asm volatile("s_waitcnt vmcnt(6)" ::: "memory");
            } else {
                asm volatile("s_waitcnt vmcnt(0)" ::: "memory");
            }
            FENCE(); __builtin_amdgcn_s_barrier(); FENCE();
            const char* ab = smb + buf * 24576;
            bf16x8 ah[4], al[4], bh[4];
            #pragma unroll
            for (int m = 0; m < 4; ++m) {
                ah[m] = *(const bf16x8*)(ab + roA(m));
                al[m] = *(const bf16x8*)(ab + 8192 + roA(m));
            }
            #pragma unroll
            for (int n = 0; n < 4; ++n) bh[n] = *(const bf16x8*)(ab + 16384 + roB(n));
            #pragma unroll
            for (int m = 0; m < 4; ++m)
                #pragma unroll
                for (int n = 0; n < 4; ++n) {
                    acc[m][n] = __builtin_amdgcn_mfma_f32_16x16x32_bf16(ah[m], bh[n], acc[m][n], 0, 0, 0);
                    acc[m][n] = __builtin_amdgcn_mfma_f32_16x16x32_bf16(al[m], bh[n], acc[m][n], 0, 0, 0);
                }
            FENCE(); __builtin_amdgcn_s_barrier(); FENCE();
            buf ^= 1;
        }
    } else {
        // ---- single-buffer (projections, off critical path): {AH,AL,BH,BL} = 32 KB ----
        auto STG = [&](int kk) {
            const ushort_t* ga = A + (long)(bm + srow) * lda + kk + scol;
            const ushort_t* gb = B + (long)(bn + srow) * lda + kk + scol;
            char* AH = smb + wave * 1024;
            char* AL = AH + 8192;
            char* BH = AH + 16384;
            char* BL = AH + 24576;
            GLOAD16(ga,     AH); GLOAD16(ga + 64 * lda,     AH + 4096);
            GLOAD16(ga + K, AL); GLOAD16(ga + K + 64 * lda, AL + 4096);
            GLOAD16(gb,     BH); GLOAD16(gb + 64 * lda,     BH + 4096);
            GLOAD16(gb + K, BL); GLOAD16(gb + K + 64 * lda, BL + 4096);
        };
        for (int kk = 0; kk < K; kk += 32) {
            STG(kk);
            asm volatile("s_waitcnt vmcnt(0)" ::: "memory");
            FENCE(); __builtin_amdgcn_s_barrier(); FENCE();
            const char* ab = smb;
            bf16x8 ah[4], al[4], bh[4], bl[4];
            #pragma unroll
            for (int m = 0; m < 4; ++m) {
                ah[m] = *(const bf16x8*)(ab + roA(m));
                al[m] = *(const bf16x8*)(ab + 8192 + roA(m));
            }
            #pragma unroll
            for (int n = 0; n < 4; ++n) {
                bh[n] = *(const bf16x8*)(ab + 16384 + roB(n));
                bl[n] = *(const bf16x8*)(ab + 24576 + roB(n));
            }
            #pragma unroll
            for (int m = 0; m < 4; ++m)
                #pragma unroll
                for (int n = 0; n < 4; ++n) {
                    acc[m][n] = __builtin_amdgcn_mfma_f32_16x16x32_bf16(ah[m], bh[n], acc[m][n], 0, 0, 0);
                    acc[m][n] = __builtin_amdgcn_mfma_f32_16x16x32_bf16(al[m], bh[n], acc[m][n], 0, 0, 0);
                    acc[m][n] = __builtin_amdgcn_mfma_f32_16x16x32_bf16(ah[m], bl[n], acc[m][n], 0, 0, 0);
                }
            FENCE(); __builtin_amdgcn_s_barrier(); FENCE();
        }
    }

    if (sym) {
        // ---- direct store (f16) ----
        #pragma unroll
        for (int m = 0; m < 4; ++m) {
            #pragma unroll
            for (int r = 0; r < 4; ++r) {
                int row = bm + wr * 64 + m * 16 + fg * 4 + r;
                float ra = rA[row];
                #pragma unroll
                for (int n = 0; n < 4; ++n) {
                    int col = bn + wc * 64 + n * 16 + fr;
                    Ch[(long)row * Nn + col] = f2h(acc[m][n][r] * ra * rB[col]);
                }
            }
        }
        if (bn > bm) {
            // ---- mirror store via LDS transpose (f16 out); 33.8 KB < 48 KB ----
            float* tbuf = (float*)smb;
            #pragma unroll
            for (int h = 0; h < 2; ++h) {
                __syncthreads();
                if (wc == h) {
                    #pragma unroll
                    for (int m = 0; m < 4; ++m)
                        #pragma unroll
                        for (int r = 0; r < 4; ++r) {
                            int row = wr * 64 + m * 16 + fg * 4 + r;
                            float ra = rA[bm + row];
                            #pragma unroll
                            for (int n = 0; n < 4; ++n) {
                                int cloc = n * 16 + fr;
                                float rb = rB[bn + h * 64 + cloc];
                                tbuf[cloc * 132 + row] = acc[m][n][r] * ra * rb;
                            }
                        }
                }
                __syncthreads();
                #pragma unroll
                for (int q = 0; q < 8; ++q) {
                    int fi = (q * 256 + tid) * 4;    // 0..8191
                    int rp = fi >> 7;                // transposed row 0..63
                    int cp = fi & 127;               // col 0..127 (step 4)
                    ushort4 val = make_ushort4(
                        f2h(tbuf[rp * 132 + cp]),     f2h(tbuf[rp * 132 + cp + 1]),
                        f2h(tbuf[rp * 132 + cp + 2]), f2h(tbuf[rp * 132 + cp + 3]));
                    *(ushort4*)&Ch[(long)(bn + h * 64 + rp) * Nn + bm + cp] = val;
                }
            }
        }
    } else {
        // ---- direct store (f32, projections) ----
        #pragma unroll
        for (int m = 0; m < 4; ++m) {
            #pragma unroll
            for (int r = 0; r < 4; ++r) {
                int row = bm + wr * 64 + m * 16 + fg * 4 + r;
                #pragma unroll
                for (int n = 0; n < 4; ++n) {
                    int col = bn + wc * 64 + n * 16 + fr;
                    Cf[(long)row * Nn + col] = acc[m][n][r];
                }
            }
        }
    }
}

// ---------------- merged top-5 per row + degree counts (packed-key, 4 waves/block) ----------------
__global__ __launch_bounds__(256) void topk_kernel(
    const ushort_t* __restrict__ he_sim, const ushort_t* __restrict__ st_sim,
    const int* __restrict__ mask,
    int* __restrict__ he_idx, int* __restrict__ st_idx,
    int* __restrict__ he_cnt, int* __restrict__ st_cnt)
{
    int gb = blockIdx.x * 4 + (threadIdx.x >> 6);
    int lane = threadIdx.x & 63;
    unsigned k0 = 0, k1 = 0, k2 = 0, k3 = 0, k4 = 0;
    int* outIdx; int* cntp;

    auto skey = [](unsigned h) -> unsigned {
        unsigned s = h >> 15;
        return h ^ (((0u - s) | 0x8000u) & 0xFFFFu);
    };
    auto insk = [&](unsigned key) {
        bool c0 = key > k0, c1 = key > k1, c2 = key > k2, c3 = key > k3, c4 = key > k4;
        k4 = c4 ? (c3 ? k3 : key) : k4;
        k3 = c3 ? (c2 ? k2 : key) : k3;
        k2 = c2 ? (c1 ? k1 : key) : k2;
        k1 = c1 ? (c0 ? k0 : key) : k1;
        k0 = c0 ? key : k0;
    };

    if (gb < NN) {
        int z = gb >> 10;
        const uint4* row8 = (const uint4*)(he_sim + (long)z * PP * PP + (long)(gb & (PP - 1)) * PP);
        outIdx = he_idx + (long)gb * K_HG;
        cntp = he_cnt + z * PP;
        #pragma unroll
        for (int it = 0; it < (PP / 8) / 64; ++it) {      // 2 iters
            int j8 = it * 64 + lane;
            uint4 u = row8[j8];
            unsigned inv = 0xFFFFu - (unsigned)(j8 * 8);
            insk((skey(u.x & 0xFFFFu) << 16) | inv);
            insk((skey(u.x >> 16)     << 16) | (inv - 1));
            insk((skey(u.y & 0xFFFFu) << 16) | (inv - 2));
            insk((skey(u.y >> 16)     << 16) | (inv - 3));
            insk((skey(u.z & 0xFFFFu) << 16) | (inv - 4));
            insk((skey(u.z >> 16)     << 16) | (inv - 5));
            insk((skey(u.w & 0xFFFFu) << 16) | (inv - 6));
            insk((skey(u.w >> 16)     << 16) | (inv - 7));
        }
    } else {
        int g2 = gb - NN;
        int z = g2 >> 11, e = g2 & (MM - 1);
        const int* mk = mask + (long)z * MM;
        outIdx = st_idx + (long)g2 * K_HG;
        cntp = st_cnt + z * MM;
        if (mk[e] == 0) {
            if (lane == 0) {
                #pragma unroll
                for (int r = 0; r < K_HG; ++r) outIdx[r] = -1;
            }
            return;
        }
        const uint4* row8 = (const uint4*)(st_sim + (long)e * MM);
        const int4*  mk4  = (const int4*)mk;
        #pragma unroll
        for (int it = 0; it < (MM / 8) / 64; ++it) {      // 4 iters
            int j8 = it * 64 + lane;
            uint4 u = row8[j8];
            int4 ma = mk4[2 * j8], mb = mk4[2 * j8 + 1];
            unsigned inv = 0xFFFFu - (unsigned)(j8 * 8);
            insk(ma.x ? ((skey(u.x & 0xFFFFu) << 16) | inv)       : 0u);
            insk(ma.y ? ((skey(u.x >> 16)     << 16) | (inv - 1)) : 0u);
            insk(ma.z ? ((skey(u.y & 0xFFFFu) << 16) | (inv - 2)) : 0u);
            insk(ma.w ? ((skey(u.y >> 16)     << 16) | (inv - 3)) : 0u);
            insk(mb.x ? ((skey(u.z & 0xFFFFu) << 16) | (inv - 4)) : 0u);
            insk(mb.y ? ((skey(u.z >> 16)     << 16) | (inv - 5)) : 0u);
            insk(mb.z ? ((skey(u.w & 0xFFFFu) << 16) | (inv - 6)) : 0u);
            insk(mb.w ? ((skey(u.w >> 16)     << 16) | (inv - 7)) : 0u);
        }
    }

    // 5 rounds of wave max merge (keys unique -> exact pop)
    #pragma unroll
    for (int r = 0; r < K_HG; ++r) {
        unsigned bk = k0;
        for (int o = 32; o > 0; o >>= 1) {
            unsigned ok = (unsigned)__shfl_xor((int)bk, o, 64);
            bk = ok > bk ? ok : bk;
        }
        if (lane == 0) {
            int bi = (int)(0xFFFFu - (bk & 0xFFFFu));
            outIdx[r] = bi;
            atomicAdd(&cntp[bi], 1);
        }
        if (k0 == bk) {
            k0 = k1; k1 = k2; k2 = k3; k3 = k4; k4 = 0;
        }
    }
}

// ---------------- merged per-edge value (bf16 out) + capacity-CSR fill ----------------
__global__ __launch_bounds__(256) void edge_kernel(
    const int* __restrict__ he_idx, const int* __restrict__ st_idx,
    const float* __restrict__ Xw_he, const float* __restrict__ Xw_st,
    const int* __restrict__ he_cnt, const int* __restrict__ st_cnt,
    int* __restrict__ he_cur, int* __restrict__ st_cur,
    int* __restrict__ he_inv, int* __restrict__ st_inv,
    ushort_t* __restrict__ he_ev, ushort_t* __restrict__ st_ev)
{
    int b = blockIdx.x;
    const int *idx, *cnt; const float* Xw;
    int *cur, *inv; ushort_t* ev;
    int ge, gbase, rowsPerZ; long xwBase;
    if (b < NN) {
        ge = b; int z = ge >> 10;
        idx = he_idx; Xw = Xw_he; cnt = he_cnt;
        cur = he_cur; inv = he_inv; ev = he_ev;
        rowsPerZ = PP; gbase = z * PP; xwBase = (long)z * PP;
    } else {
        ge = b - NN; int z = ge >> 11;
        idx = st_idx; Xw = Xw_st; cnt = st_cnt;
        cur = st_cur; inv = st_inv; ev = st_ev;
        rowsPerZ = MM; gbase = z * MM; xwBase = 0;
    }
    int mm[K_HG];
    #pragma unroll
    for (int k = 0; k < K_HG; ++k) mm[k] = idx[(long)ge * K_HG + k];
    if (mm[0] < 0) return;   // masked-out ST edge
    int d = threadIdx.x;
    float val = 0.0f;
    #pragma unroll
    for (int k = 0; k < K_HG; ++k) {
        int m = mm[k];
        if (m < 0 || m >= rowsPerZ) continue;
        float w = rsqrtf(fmaxf((float)cnt[gbase + m], EPSF));
        val += w * Xw[(xwBase + m) * D_OUT + d];
    }
    ev[(long)ge * D_OUT + d] = f2bf(val * (1.0f / (float)K_HG));
    if (d < K_HG) {
        int m = mm[d];
        if (m >= 0 && m < rowsPerZ) {
            int g = gbase + m;
            int pos = atomicAdd(&cur[g], 1);
            if (pos < DEG_CAP) inv[(long)g * DEG_CAP + pos] = ge;
        }
    }
}

// ---------------- node gather + Dv^-1/2 + GELU + atomic pool into z ----------------
__global__ __launch_bounds__(256) void pool_gather_kernel(
    const ushort_t* __restrict__ he_ev, const ushort_t* __restrict__ st_ev,
    const int* __restrict__ he_cnt, const int* __restrict__ st_cnt,
    const int* __restrict__ he_inv, const int* __restrict__ st_inv,
    const int* __restrict__ mask,
    float* __restrict__ zacc_he, float* __restrict__ zacc_st)
{
    int blk = blockIdx.x;
    const ushort_t* ev; const int *cnt, *inv, *msk = nullptr;
    float* zt; int gbase, i0;
    if (blk < VV * HE_NCH) {
        int z = blk / HE_NCH, c = blk % HE_NCH;
        ev = he_ev; cnt = he_cnt; inv = he_inv;
        zt = zacc_he + z * D_OUT;
        gbase = z * PP; i0 = c * POOL_CHUNK;
    } else {
        int b2 = blk - VV * HE_NCH;
        int z = b2 / ST_NCH, c = b2 % ST_NCH;
        ev = st_ev; cnt = st_cnt; inv = st_inv;
        msk = mask;
        zt = zacc_st + z * D_OUT;
        gbase = z * MM; i0 = c * POOL_CHUNK;
    }
    int d = threadIdx.x;
    float s = 0.0f;
    bool any = false;
    #pragma unroll
    for (int i = 0; i < POOL_CHUNK; ++i) {
        int g = gbase + i0 + i;
        if (msk && msk[g] == 0) continue;
        any = true;
        int cn = cnt[g];
        const int* ip = inv + (long)g * DEG_CAP;
        float a = 0.0f;
        for (int e = 0; e < cn; ++e)
            a += bf2f(ev[(long)ip[e] * D_OUT + d]);
        float w = rsqrtf(fmaxf((float)cn, EPSF));
        float x = w * a;
        s += 0.5f * x * (1.0f + erff(x * 0.70710678118654752f));   // exact GELU
    }
    if (any || !msk) atomicAdd(&zt[d], s);
}

// ---------------- final: divide + l2norm + contrastive loss ----------------
__global__ __launch_bounds__(64) void final_kernel(const float* __restrict__ zacc_he,
                                                   const float* __restrict__ zacc_st,
                                                   const int* __restrict__ maskcnt,
                                                   float* __restrict__ out) {
    __shared__ float he[VV][D_OUT];
    __shared__ float st[VV][D_OUT];
    __shared__ float lg[VV][VV];
    __shared__ float rn_he[VV], rn_st[VV];
    int t = threadIdx.x;
    for (int i = t; i < VV * D_OUT; i += 64) {
        int v = i >> 8;
        he[v][i & 255] = zacc_he[i] / (float)PP;
        st[v][i & 255] = zacc_st[i] / (float)maskcnt[v];
    }
    __syncthreads();
    if (t < VV) {
        float s = 0.0f;
        for (int d2 = 0; d2 < D_OUT; ++d2) s += he[t][d2] * he[t][d2];
        rn_he[t] = 1.0f / fmaxf(sqrtf(s), EPSF);
    } else if (t < 2 * VV) {
        int v = t - VV; float s = 0.0f;
        for (int d2 = 0; d2 < D_OUT; ++d2) s += st[v][d2] * st[v][d2];
        rn_st[v] = 1.0f / fmaxf(sqrtf(s), EPSF);
    }
    __syncthreads();
    int v = t >> 3, w2 = t & 7;
    float dot = 0.0f;
    for (int d2 = 0; d2 < D_OUT; ++d2) dot += he[v][d2] * st[w2][d2];
    lg[v][w2] = dot * rn_he[v] * rn_st[w2] / TEMP;
    __syncthreads();
    if (t == 0) {
        float l1 = 0.0f, l2 = 0.0f;
        for (int i = 0; i < VV; ++i) {
            float mx = -1e30f;
            for (int jj = 0; jj < VV; ++jj) mx = fmaxf(mx, lg[i][jj]);
            float se = 0.0f;
            for (int jj = 0; jj < VV; ++jj) se += expf(lg[i][jj] - mx);
            l1 += lg[i][i] - (mx + logf(se));
            float mx2 = -1e30f;
            for (int jj = 0; jj < VV; ++jj) mx2 = fmaxf(mx2, lg[jj][i]);
            float se2 = 0.0f;
            for (int jj = 0; jj < VV; ++jj) se2 += expf(lg[jj][i] - mx2);
            l2 += lg[i][i] - (mx2 + logf(se2));
        }
        out[0] = 0.5f * (-(l1 / (float)VV) - (l2 / (float)VV));
    }
}

// ---------------- launch ----------------
extern "C" void kernel_launch(void* const* d_in, const int* in_sizes, int n_in,
                              void* d_out, int out_size, void* d_ws, size_t ws_size,
                              hipStream_t stream) {
    const float* F    = (const float*)d_in[0];
    const float* T    = (const float*)d_in[1];
    const float* E    = (const float*)d_in[3];
    const float* S    = (const float*)d_in[4];
    const float* W_he = (const float*)d_in[5];
    const float* W_st = (const float*)d_in[6];
    float* out = (float*)d_out;

    size_t off = 0;
    auto take = [&](size_t bytes) -> void* {
        void* p = (char*)d_ws + off;
        off += (bytes + 255) & ~(size_t)255;
        return p;
    };
    ushort_t* Fs    = (ushort_t*)take((size_t)NN * 2 * HE_DIM * 2);   // 33.5 MB
    ushort_t* Es    = (ushort_t*)take((size_t)MM * 2 * ST_DIM * 2);   // 4.2 MB
    ushort_t* Whes  = (ushort_t*)take((size_t)D_OUT * 2 * HE_DIM * 2);
    ushort_t* Wsts  = (ushort_t*)take((size_t)D_OUT * 2 * ST_DIM * 2);
    float* Xw_he    = (float*)take((size_t)NN * D_OUT * 4);           // 8 MB
    float* Xw_st    = (float*)take((size_t)MM * D_OUT * 4);           // 2 MB
    float* rnF      = (float*)take((size_t)NN * 4);
    float* rnE      = (float*)take((size_t)MM * 4);
    int*   mask     = (int*)  take((size_t)VV * MM * 4);
    int*   maskcnt  = (int*)  take((size_t)VV * 4);
    ushort_t* he_sim = (ushort_t*)take((size_t)VV * PP * PP * 2);     // 16 MB (f16)
    ushort_t* st_sim = (ushort_t*)take((size_t)MM * MM * 2);          // 8 MB (f16)
    int*   he_idx   = (int*)  take((size_t)NN * K_HG * 4);
    int*   st_idx   = (int*)  take((size_t)VV * MM * K_HG * 4);
    // zero-init region (zeroed inside prep): counts + cursors + z accumulators
    size_t zero_beg = off;
    int*   he_cnt   = (int*)  take((size_t)NN * 4);
    int*   st_cnt   = (int*)  take((size_t)VV * MM * 4);
    int*   he_cur   = (int*)  take((size_t)NN * 4);
    int*   st_cur   = (int*)  take((size_t)VV * MM * 4);
    float* zacc_he  = (float*)take((size_t)VV * D_OUT * 4);
    float* zacc_st  = (float*)take((size_t)VV * D_OUT * 4);
    size_t zero_end = off;
    int*   he_inv   = (int*)  take((size_t)NN * DEG_CAP * 4);         // 3 MB
    int*   st_inv   = (int*)  take((size_t)VV * MM * DEG_CAP * 4);    // 6 MB
    ushort_t* he_ev = (ushort_t*)take((size_t)NN * D_OUT * 2);        // 4 MB (bf16)
    ushort_t* st_ev = (ushort_t*)take((size_t)VV * MM * D_OUT * 2);   // 8 MB (bf16)

    int nZeroInts = (int)((zero_end - zero_beg) / 4);

    // split hi/lo + row norms + centroids/mask + zeroing (one launch)
    prep_kernel<<<NPREP + VV, 256, 0, stream>>>(F, E, W_he, W_st, T, S,
                                                Fs, Es, Whes, Wsts, rnF, rnE,
                                                mask, maskcnt,
                                                (int*)((char*)d_ws + zero_beg), nZeroInts);

    // all four GEMMs in one grouped launch (48 KB LDS -> 3 blocks/CU)
    gemm_grouped<<<NB_ALL, 256, 0, stream>>>(Fs, Es, Whes, Wsts,
                                             he_sim, st_sim, Xw_he, Xw_st,
                                             rnF, rnE);

    // top-5 + degree counts (packed integer keys, 4 waves/block)
    topk_kernel<<<(NN + VV * MM) / 4, 256, 0, stream>>>(he_sim, st_sim, mask,
                                                        he_idx, st_idx, he_cnt, st_cnt);
    // per-edge values (bf16) + capacity-based inverse fill
    edge_kernel<<<NN + VV * MM, 256, 0, stream>>>(he_idx, st_idx, Xw_he, Xw_st,
                                                  he_cnt, st_cnt,
                                                  he_cur, st_cur, he_inv, st_inv,
                                                  he_ev, st_ev);
    // gather + gelu + atomic pool directly into z accumulators
    pool_gather_kernel<<<VV * HE_NCH + VV * ST_NCH, 256, 0, stream>>>(
        he_ev, st_ev, he_cnt, st_cnt, he_inv, st_inv,
        mask, zacc_he, zacc_st);
    // divide + loss
    final_kernel<<<1, 64, 0, stream>>>(zacc_he, zacc_st, maskcnt, out);
}

// Round 20
// 147.146 us; speedup vs baseline: 1.1134x; 1.1134x over previous
//
#include <hip/hip_runtime.h>
#include <hip/hip_bf16.h>
#include <hip/hip_fp16.h>
#include <math.h>

// ---------------- problem constants ----------------
#define NN      8192
#define VV      8
#define PP      1024      // N / V
#define MM      2048
#define HE_DIM  1024
#define ST_DIM  512
#define D_OUT   256
#define K_HG    5
#define RADIUS  150.0f
#define TEMP    0.07f
#define EPSF    1e-12f

#define POOL_CHUNK 4
#define HE_NCH  (PP / POOL_CHUNK)   // 256
#define ST_NCH  (MM / POOL_CHUNK)   // 512
#define DEG_CAP 96                  // max node in-degree (KNN in-degree max ~20)

// grouped-GEMM block ranges
#define HE_TRI   36                 // 8x8 upper triangle
#define ST_TRI   136                // 16x16 upper triangle
#define NB_HE    (VV * HE_TRI)      // 288
#define NB_ST    ST_TRI             // 136
#define NB_PH    ((NN / 128) * (D_OUT / 128))   // 128
#define NB_PS    ((MM / 128) * (D_OUT / 128))   // 32
#define NB_ALL   (NB_HE + NB_ST + NB_PH + NB_PS) // 584 = 8 * 73

#define NPREP   (NN + MM + 2 * D_OUT)   // rows handled by prep; +VV extra blocks

typedef __bf16 bf16x8 __attribute__((ext_vector_type(8)));
typedef float  f32x4  __attribute__((ext_vector_type(4)));
typedef unsigned short ushort_t;

typedef __attribute__((address_space(1))) void gvoid;
typedef __attribute__((address_space(3))) void svoid;
#define GLOAD16(g, l) __builtin_amdgcn_global_load_lds((gvoid*)(g), (svoid*)(l), 16, 0, 0)
#define FENCE() asm volatile("" ::: "memory")

__device__ __forceinline__ ushort_t f2bf(float x) {
    unsigned int b = __float_as_uint(x);
    return (ushort_t)((b + 0x7fffu + ((b >> 16) & 1u)) >> 16);   // RNE
}
__device__ __forceinline__ float bf2f(ushort_t h) {
    return __uint_as_float(((unsigned int)h) << 16);
}
__device__ __forceinline__ ushort_t f2h(float x) {
    return __half_as_ushort(__float2half_rn(x));
}

// ---------------- fused: split + rownorm + (centers/mask/zero in tail blocks) ----------------
__global__ __launch_bounds__(256) void prep_kernel(
    const float* __restrict__ F, const float* __restrict__ E,
    const float* __restrict__ Whe, const float* __restrict__ Wst,
    const float* __restrict__ T, const float* __restrict__ S,
    ushort_t* __restrict__ Fs, ushort_t* __restrict__ Es,
    ushort_t* __restrict__ Whes, ushort_t* __restrict__ Wsts,
    float* __restrict__ rnF, float* __restrict__ rnE,
    int* __restrict__ mask, int* __restrict__ maskcnt,
    int* __restrict__ zeroPtr, int nZeroInts)
{
    int b = blockIdx.x;
    if (b >= NPREP) {
        int v = b - NPREP;
        int per = (nZeroInts + VV - 1) / VV;
        for (int i = threadIdx.x; i < per; i += 256) {
            int idx = v * per + i;
            if (idx < nZeroInts) zeroPtr[idx] = 0;
        }
        float sx = 0.0f, sy = 0.0f;
        for (int i = threadIdx.x; i < PP; i += 256) {
            sx += T[(long)(v * PP + i) * 2 + 0];
            sy += T[(long)(v * PP + i) * 2 + 1];
        }
        __shared__ float rx[256], ry[256];
        __shared__ int   rc[256];
        rx[threadIdx.x] = sx; ry[threadIdx.x] = sy; __syncthreads();
        for (int o = 128; o > 0; o >>= 1) {
            if (threadIdx.x < o) { rx[threadIdx.x] += rx[threadIdx.x + o]; ry[threadIdx.x] += ry[threadIdx.x + o]; }
            __syncthreads();
        }
        float cx = rx[0] / (float)PP, cy = ry[0] / (float)PP;
        __syncthreads();
        int cnt = 0;
        for (int m = threadIdx.x; m < MM; m += 256) {
            float dx = cx - S[m * 2 + 0];
            float dy = cy - S[m * 2 + 1];
            int in = (sqrtf(dx * dx + dy * dy) < RADIUS) ? 1 : 0;
            mask[v * MM + m] = in;
            cnt += in;
        }
        rc[threadIdx.x] = cnt; __syncthreads();
        for (int o = 128; o > 0; o >>= 1) {
            if (threadIdx.x < o) rc[threadIdx.x] += rc[threadIdx.x + o];
            __syncthreads();
        }
        if (threadIdx.x == 0) maskcnt[v] = rc[0];
        return;
    }
    const float* src; ushort_t* dst; float* rn; int K; long row;
    if (b < NN)                    { src = F;   dst = Fs;   rn = rnF;    K = HE_DIM; row = b; }
    else if (b < NN + MM)          { src = E;   dst = Es;   rn = rnE;    K = ST_DIM; row = b - NN; }
    else if (b < NN + MM + D_OUT)  { src = Whe; dst = Whes; rn = nullptr; K = HE_DIM; row = b - NN - MM; }
    else                           { src = Wst; dst = Wsts; rn = nullptr; K = ST_DIM; row = b - NN - MM - D_OUT; }
    const float4* srow = (const float4*)(src + row * (long)K);
    ushort_t* drow = dst + row * 2L * K;
    float s = 0.0f;
    for (int j4 = threadIdx.x; j4 < (K >> 2); j4 += 256) {
        float4 x = srow[j4];
        float xs[4] = {x.x, x.y, x.z, x.w};
        ushort_t hs[4], ls[4];
        #pragma unroll
        for (int t = 0; t < 4; ++t) {
            hs[t] = f2bf(xs[t]);
            ls[t] = f2bf(xs[t] - bf2f(hs[t]));    // lo residual
            s += xs[t] * xs[t];
        }
        *(ushort4*)(drow + j4 * 4)     = make_ushort4(hs[0], hs[1], hs[2], hs[3]);
        *(ushort4*)(drow + K + j4 * 4) = make_ushort4(ls[0], ls[1], ls[2], ls[3]);
    }
    if (rn) {
        __shared__ float red[256];
        red[threadIdx.x] = s; __syncthreads();
        for (int o = 128; o > 0; o >>= 1) {
            if (threadIdx.x < o) red[threadIdx.x] += red[threadIdx.x + o];
            __syncthreads();
        }
        if (threadIdx.x == 0) rn[row] = 1.0f / fmaxf(sqrtf(red[0]), EPSF);
    }
}

// ---------------- grouped split-bf16 MFMA GEMM, per-op pipeline plan (R18 config) ----------------
// nseg=1 (HE Gram):  3-buf {AH,BH},    depth-2 prefetch, f16 sim out
// nseg=2 (ST Gram):  3-buf {AH,AL,BH}, depth-2 prefetch, f16 sim out
// nseg=3 (proj):     2-buf {AH,AL,BH,BL}, depth-1, f32 out
__global__ __launch_bounds__(256) void gemm_grouped(
    const ushort_t* __restrict__ Fs, const ushort_t* __restrict__ Es,
    const ushort_t* __restrict__ Whes, const ushort_t* __restrict__ Wsts,
    ushort_t* __restrict__ he_sim, ushort_t* __restrict__ st_sim,
    float* __restrict__ Xw_he, float* __restrict__ Xw_st,
    const float* __restrict__ rnF, const float* __restrict__ rnE)
{
    // Balanced XCD map: XCD k owns region k's 36 HE tiles; round-robin rest.
    int bid = blockIdx.x;
    int xcd = bid & 7, j = bid >> 3;    // 584 = 8*73, bijective
    int id = (j < HE_TRI) ? (xcd * HE_TRI + j)
                          : (NB_HE + (j - HE_TRI) * 8 + xcd);

    const ushort_t *A, *B; ushort_t *Ch = nullptr; float *Cf = nullptr;
    const float *rA = nullptr, *rB = nullptr;
    int K, Nn, bm, bn, sym, nseg;
    if (id < NB_HE) {
        int z = id / HE_TRI, t = id - z * HE_TRI;
        int i = 0;
        while (t >= 8 - i) { t -= 8 - i; ++i; }
        bm = i * 128; bn = (i + t) * 128;
        A = B = Fs + (long)z * PP * 2 * HE_DIM;
        Ch = he_sim + (long)z * PP * PP;
        rA = rB = rnF + z * PP;
        K = HE_DIM; Nn = PP; sym = 1; nseg = 1;
    } else if (id < NB_HE + NB_ST) {
        int t = id - NB_HE;
        int i = 0;
        while (t >= 16 - i) { t -= 16 - i; ++i; }
        bm = i * 128; bn = (i + t) * 128;
        A = B = Es; Ch = st_sim; rA = rB = rnE;
        K = ST_DIM; Nn = MM; sym = 1; nseg = 2;
    } else if (id < NB_HE + NB_ST + NB_PH) {
        int t = id - (NB_HE + NB_ST);
        bm = (t >> 1) * 128; bn = (t & 1) * 128;
        A = Fs; B = Whes; Cf = Xw_he;
        K = HE_DIM; Nn = D_OUT; sym = 0; nseg = 3;
    } else {
        int t = id - (NB_HE + NB_ST + NB_PH);
        bm = (t >> 1) * 128; bn = (t & 1) * 128;
        A = Es; B = Wsts; Cf = Xw_st;
        K = ST_DIM; Nn = D_OUT; sym = 0; nseg = 3;
    }

    __shared__ ushort_t sm[36864];   // 72 KB; per-nseg layout (aliased)
    char* const smb = (char*)&sm[0];
    const int tid  = threadIdx.x;
    const int lane = tid & 63, wave = tid >> 6;
    const int wr = wave >> 1, wc = wave & 1;
    const int fr = lane & 15, fg = lane >> 4;

    const long lda = 2L * K;
    const int srow = wave * 16 + (lane >> 2);
    const int scol = (((lane & 3) ^ ((srow >> 1) & 3)) * 8);  // pre-swizzled src col

    f32x4 acc[4][4] = {};

    auto roA = [&](int m) { int row = wr * 64 + m * 16 + fr;
                            return row * 64 + ((fg ^ ((row >> 1) & 3)) * 16); };
    auto roB = [&](int n) { int row = wc * 64 + n * 16 + fr;
                            return row * 64 + ((fg ^ ((row >> 1) & 3)) * 16); };

    if (nseg == 1) {
        auto STG = [&](int kk, int b) {
            const ushort_t* ga = A + (long)(bm + srow) * lda + kk + scol;
            const ushort_t* gb = B + (long)(bn + srow) * lda + kk + scol;
            char* AH = smb + b * 16384 + wave * 1024;
            char* BH = smb + b * 16384 + 8192 + wave * 1024;
            GLOAD16(ga, AH); GLOAD16(ga + 64 * lda, AH + 4096);
            GLOAD16(gb, BH); GLOAD16(gb + 64 * lda, BH + 4096);
        };
        STG(0, 0); STG(32, 1);
        int buf = 0;
        for (int kk = 0; kk < K; kk += 32) {
            if (kk + 64 < K) {
                STG(kk + 64, buf == 0 ? 2 : buf - 1);
                asm volatile("s_waitcnt vmcnt(8)" ::: "memory");
            } else if (kk + 32 < K) {
                asm volatile("s_waitcnt vmcnt(4)" ::: "memory");
            } else {
                asm volatile("s_waitcnt vmcnt(0)" ::: "memory");
            }
            FENCE(); __builtin_amdgcn_s_barrier(); FENCE();
            const char* ab = smb + buf * 16384;
            bf16x8 ah[4], bh[4];
            #pragma unroll
            for (int m = 0; m < 4; ++m) ah[m] = *(const bf16x8*)(ab + roA(m));
            #pragma unroll
            for (int n = 0; n < 4; ++n) bh[n] = *(const bf16x8*)(ab + 8192 + roB(n));
            #pragma unroll
            for (int m = 0; m < 4; ++m)
                #pragma unroll
                for (int n = 0; n < 4; ++n)
                    acc[m][n] = __builtin_amdgcn_mfma_f32_16x16x32_bf16(ah[m], bh[n], acc[m][n], 0, 0, 0);
            FENCE(); __builtin_amdgcn_s_barrier(); FENCE();
            buf = (buf == 2) ? 0 : buf + 1;
        }
    } else if (nseg == 2) {
        auto STG = [&](int kk, int b) {
            const ushort_t* ga = A + (long)(bm + srow) * lda + kk + scol;
            const ushort_t* gb = B + (long)(bn + srow) * lda + kk + scol;
            char* AH = smb + b * 24576 + wave * 1024;
            char* AL = AH + 8192;
            char* BH = AH + 16384;
            GLOAD16(ga,     AH); GLOAD16(ga + 64 * lda,     AH + 4096);
            GLOAD16(ga + K, AL); GLOAD16(ga + K + 64 * lda, AL + 4096);
            GLOAD16(gb,     BH); GLOAD16(gb + 64 * lda,     BH + 4096);
        };
        STG(0, 0); STG(32, 1);
        int buf = 0;
        for (int kk = 0; kk < K; kk += 32) {
            if (kk + 64 < K) {
                STG(kk + 64, buf == 0 ? 2 : buf - 1);
                asm volatile("s_waitcnt vmcnt(12)" ::: "memory");
            } else if (kk + 32 < K) {
                asm volatile("s_waitcnt vmcnt(6)" ::: "memory");
            } else {
                asm volatile("s_waitcnt vmcnt(0)" ::: "memory");
            }
            FENCE(); __builtin_amdgcn_s_barrier(); FENCE();
            const char* ab = smb + buf * 24576;
            bf16x8 ah[4], al[4], bh[4];
            #pragma unroll
            for (int m = 0; m < 4; ++m) {
                ah[m] = *(const bf16x8*)(ab + roA(m));
                al[m] = *(const bf16x8*)(ab + 8192 + roA(m));
            }
            #pragma unroll
            for (int n = 0; n < 4; ++n) bh[n] = *(const bf16x8*)(ab + 16384 + roB(n));
            #pragma unroll
            for (int m = 0; m < 4; ++m)
                #pragma unroll
                for (int n = 0; n < 4; ++n) {
                    acc[m][n] = __builtin_amdgcn_mfma_f32_16x16x32_bf16(ah[m], bh[n], acc[m][n], 0, 0, 0);
                    acc[m][n] = __builtin_amdgcn_mfma_f32_16x16x32_bf16(al[m], bh[n], acc[m][n], 0, 0, 0);
                }
            FENCE(); __builtin_amdgcn_s_barrier(); FENCE();
            buf = (buf == 2) ? 0 : buf + 1;
        }
    } else {
        auto STG = [&](int kk, int b) {
            const ushort_t* ga = A + (long)(bm + srow) * lda + kk + scol;
            const ushort_t* gb = B + (long)(bn + srow) * lda + kk + scol;
            char* AH = smb + b * 32768 + wave * 1024;
            char* AL = AH + 8192;
            char* BH = AH + 16384;
            char* BL = AH + 24576;
            GLOAD16(ga,     AH); GLOAD16(ga + 64 * lda,     AH + 4096);
            GLOAD16(ga + K, AL); GLOAD16(ga + K + 64 * lda, AL + 4096);
            GLOAD16(gb,     BH); GLOAD16(gb + 64 * lda,     BH + 4096);
            GLOAD16(gb + K, BL); GLOAD16(gb + K + 64 * lda, BL + 4096);
        };
        STG(0, 0);
        int buf = 0;
        for (int kk = 0; kk < K; kk += 32) {
            if (kk + 32 < K) {
                STG(kk + 32, buf ^ 1);
                asm volatile("s_waitcnt vmcnt(8)" ::: "memory");
            } else {
                asm volatile("s_waitcnt vmcnt(0)" ::: "memory");
            }
            FENCE(); __builtin_amdgcn_s_barrier(); FENCE();
            const char* ab = smb + buf * 32768;
            bf16x8 ah[4], al[4], bh[4], bl[4];
            #pragma unroll
            for (int m = 0; m < 4; ++m) {
                ah[m] = *(const bf16x8*)(ab + roA(m));
                al[m] = *(const bf16x8*)(ab + 8192 + roA(m));
            }
            #pragma unroll
            for (int n = 0; n < 4; ++n) {
                bh[n] = *(const bf16x8*)(ab + 16384 + roB(n));
                bl[n] = *(const bf16x8*)(ab + 24576 + roB(n));
            }
            #pragma unroll
            for (int m = 0; m < 4; ++m)
                #pragma unroll
                for (int n = 0; n < 4; ++n) {
                    acc[m][n] = __builtin_amdgcn_mfma_f32_16x16x32_bf16(ah[m], bh[n], acc[m][n], 0, 0, 0);
                    acc[m][n] = __builtin_amdgcn_mfma_f32_16x16x32_bf16(al[m], bh[n], acc[m][n], 0, 0, 0);
                    acc[m][n] = __builtin_amdgcn_mfma_f32_16x16x32_bf16(ah[m], bl[n], acc[m][n], 0, 0, 0);
                }
            FENCE(); __builtin_amdgcn_s_barrier(); FENCE();
            buf ^= 1;
        }
    }

    if (sym) {
        // ---- direct store (f16) ----
        #pragma unroll
        for (int m = 0; m < 4; ++m) {
            #pragma unroll
            for (int r = 0; r < 4; ++r) {
                int row = bm + wr * 64 + m * 16 + fg * 4 + r;
                float ra = rA[row];
                #pragma unroll
                for (int n = 0; n < 4; ++n) {
                    int col = bn + wc * 64 + n * 16 + fr;
                    Ch[(long)row * Nn + col] = f2h(acc[m][n][r] * ra * rB[col]);
                }
            }
        }
        if (bn > bm) {
            // ---- mirror store via LDS transpose (f16 out) ----
            float* tbuf = (float*)smb;   // 64 x 132 f32
            #pragma unroll
            for (int h = 0; h < 2; ++h) {
                __syncthreads();
                if (wc == h) {
                    #pragma unroll
                    for (int m = 0; m < 4; ++m)
                        #pragma unroll
                        for (int r = 0; r < 4; ++r) {
                            int row = wr * 64 + m * 16 + fg * 4 + r;
                            float ra = rA[bm + row];
                            #pragma unroll
                            for (int n = 0; n < 4; ++n) {
                                int cloc = n * 16 + fr;
                                float rb = rB[bn + h * 64 + cloc];
                                tbuf[cloc * 132 + row] = acc[m][n][r] * ra * rb;
                            }
                        }
                }
                __syncthreads();
                #pragma unroll
                for (int q = 0; q < 8; ++q) {
                    int fi = (q * 256 + tid) * 4;    // 0..8191
                    int rp = fi >> 7;                // transposed row 0..63
                    int cp = fi & 127;               // col 0..127 (step 4)
                    ushort4 val = make_ushort4(
                        f2h(tbuf[rp * 132 + cp]),     f2h(tbuf[rp * 132 + cp + 1]),
                        f2h(tbuf[rp * 132 + cp + 2]), f2h(tbuf[rp * 132 + cp + 3]));
                    *(ushort4*)&Ch[(long)(bn + h * 64 + rp) * Nn + bm + cp] = val;
                }
            }
        }
    } else {
        // ---- direct store (f32, projections) ----
        #pragma unroll
        for (int m = 0; m < 4; ++m) {
            #pragma unroll
            for (int r = 0; r < 4; ++r) {
                int row = bm + wr * 64 + m * 16 + fg * 4 + r;
                #pragma unroll
                for (int n = 0; n < 4; ++n) {
                    int col = bn + wc * 64 + n * 16 + fr;
                    Cf[(long)row * Nn + col] = acc[m][n][r];
                }
            }
        }
    }
}

// ---------------- merged top-5 per row + degree counts (packed-key, 4 waves/block) ----------------
__global__ __launch_bounds__(256) void topk_kernel(
    const ushort_t* __restrict__ he_sim, const ushort_t* __restrict__ st_sim,
    const int* __restrict__ mask,
    int* __restrict__ he_idx, int* __restrict__ st_idx,
    int* __restrict__ he_cnt, int* __restrict__ st_cnt)
{
    int gb = blockIdx.x * 4 + (threadIdx.x >> 6);
    int lane = threadIdx.x & 63;
    unsigned k0 = 0, k1 = 0, k2 = 0, k3 = 0, k4 = 0;
    int* outIdx; int* cntp;

    auto skey = [](unsigned h) -> unsigned {
        unsigned s = h >> 15;
        return h ^ (((0u - s) | 0x8000u) & 0xFFFFu);
    };
    auto insk = [&](unsigned key) {
        bool c0 = key > k0, c1 = key > k1, c2 = key > k2, c3 = key > k3, c4 = key > k4;
        k4 = c4 ? (c3 ? k3 : key) : k4;
        k3 = c3 ? (c2 ? k2 : key) : k3;
        k2 = c2 ? (c1 ? k1 : key) : k2;
        k1 = c1 ? (c0 ? k0 : key) : k1;
        k0 = c0 ? key : k0;
    };

    if (gb < NN) {
        int z = gb >> 10;
        const uint4* row8 = (const uint4*)(he_sim + (long)z * PP * PP + (long)(gb & (PP - 1)) * PP);
        outIdx = he_idx + (long)gb * K_HG;
        cntp = he_cnt + z * PP;
        #pragma unroll
        for (int it = 0; it < (PP / 8) / 64; ++it) {      // 2 iters
            int j8 = it * 64 + lane;
            uint4 u = row8[j8];
            unsigned inv = 0xFFFFu - (unsigned)(j8 * 8);
            insk((skey(u.x & 0xFFFFu) << 16) | inv);
            insk((skey(u.x >> 16)     << 16) | (inv - 1));
            insk((skey(u.y & 0xFFFFu) << 16) | (inv - 2));
            insk((skey(u.y >> 16)     << 16) | (inv - 3));
            insk((skey(u.z & 0xFFFFu) << 16) | (inv - 4));
            insk((skey(u.z >> 16)     << 16) | (inv - 5));
            insk((skey(u.w & 0xFFFFu) << 16) | (inv - 6));
            insk((skey(u.w >> 16)     << 16) | (inv - 7));
        }
    } else {
        int g2 = gb - NN;
        int z = g2 >> 11, e = g2 & (MM - 1);
        const int* mk = mask + (long)z * MM;
        outIdx = st_idx + (long)g2 * K_HG;
        cntp = st_cnt + z * MM;
        if (mk[e] == 0) {
            if (lane == 0) {
                #pragma unroll
                for (int r = 0; r < K_HG; ++r) outIdx[r] = -1;
            }
            return;
        }
        const uint4* row8 = (const uint4*)(st_sim + (long)e * MM);
        const int4*  mk4  = (const int4*)mk;
        #pragma unroll
        for (int it = 0; it < (MM / 8) / 64; ++it) {      // 4 iters
            int j8 = it * 64 + lane;
            uint4 u = row8[j8];
            int4 ma = mk4[2 * j8], mb = mk4[2 * j8 + 1];
            unsigned inv = 0xFFFFu - (unsigned)(j8 * 8);
            insk(ma.x ? ((skey(u.x & 0xFFFFu) << 16) | inv)       : 0u);
            insk(ma.y ? ((skey(u.x >> 16)     << 16) | (inv - 1)) : 0u);
            insk(ma.z ? ((skey(u.y & 0xFFFFu) << 16) | (inv - 2)) : 0u);
            insk(ma.w ? ((skey(u.y >> 16)     << 16) | (inv - 3)) : 0u);
            insk(mb.x ? ((skey(u.z & 0xFFFFu) << 16) | (inv - 4)) : 0u);
            insk(mb.y ? ((skey(u.z >> 16)     << 16) | (inv - 5)) : 0u);
            insk(mb.z ? ((skey(u.w & 0xFFFFu) << 16) | (inv - 6)) : 0u);
            insk(mb.w ? ((skey(u.w >> 16)     << 16) | (inv - 7)) : 0u);
        }
    }

    // 5 rounds of wave max merge (keys unique -> exact pop)
    #pragma unroll
    for (int r = 0; r < K_HG; ++r) {
        unsigned bk = k0;
        for (int o = 32; o > 0; o >>= 1) {
            unsigned ok = (unsigned)__shfl_xor((int)bk, o, 64);
            bk = ok > bk ? ok : bk;
        }
        if (lane == 0) {
            int bi = (int)(0xFFFFu - (bk & 0xFFFFu));
            outIdx[r] = bi;
            atomicAdd(&cntp[bi], 1);
        }
        if (k0 == bk) {
            k0 = k1; k1 = k2; k2 = k3; k3 = k4; k4 = 0;
        }
    }
}

// ---------------- merged per-edge value (bf16 out) + capacity-CSR fill ----------------
__global__ __launch_bounds__(256) void edge_kernel(
    const int* __restrict__ he_idx, const int* __restrict__ st_idx,
    const float* __restrict__ Xw_he, const float* __restrict__ Xw_st,
    const int* __restrict__ he_cnt, const int* __restrict__ st_cnt,
    int* __restrict__ he_cur, int* __restrict__ st_cur,
    int* __restrict__ he_inv, int* __restrict__ st_inv,
    ushort_t* __restrict__ he_ev, ushort_t* __restrict__ st_ev)
{
    int b = blockIdx.x;
    const int *idx, *cnt; const float* Xw;
    int *cur, *inv; ushort_t* ev;
    int ge, gbase, rowsPerZ; long xwBase;
    if (b < NN) {
        ge = b; int z = ge >> 10;
        idx = he_idx; Xw = Xw_he; cnt = he_cnt;
        cur = he_cur; inv = he_inv; ev = he_ev;
        rowsPerZ = PP; gbase = z * PP; xwBase = (long)z * PP;
    } else {
        ge = b - NN; int z = ge >> 11;
        idx = st_idx; Xw = Xw_st; cnt = st_cnt;
        cur = st_cur; inv = st_inv; ev = st_ev;
        rowsPerZ = MM; gbase = z * MM; xwBase = 0;
    }
    int mm[K_HG];
    #pragma unroll
    for (int k = 0; k < K_HG; ++k) mm[k] = idx[(long)ge * K_HG + k];
    if (mm[0] < 0) return;   // masked-out ST edge
    int d = threadIdx.x;
    float val = 0.0f;
    #pragma unroll
    for (int k = 0; k < K_HG; ++k) {
        int m = mm[k];
        if (m < 0 || m >= rowsPerZ) continue;
        float w = rsqrtf(fmaxf((float)cnt[gbase + m], EPSF));
        val += w * Xw[(xwBase + m) * D_OUT + d];
    }
    ev[(long)ge * D_OUT + d] = f2bf(val * (1.0f / (float)K_HG));
    if (d < K_HG) {
        int m = mm[d];
        if (m >= 0 && m < rowsPerZ) {
            int g = gbase + m;
            int pos = atomicAdd(&cur[g], 1);
            if (pos < DEG_CAP) inv[(long)g * DEG_CAP + pos] = ge;
        }
    }
}

// ---------------- node gather + Dv^-1/2 + GELU + atomic pool into z ----------------
__global__ __launch_bounds__(256) void pool_gather_kernel(
    const ushort_t* __restrict__ he_ev, const ushort_t* __restrict__ st_ev,
    const int* __restrict__ he_cnt, const int* __restrict__ st_cnt,
    const int* __restrict__ he_inv, const int* __restrict__ st_inv,
    const int* __restrict__ mask,
    float* __restrict__ zacc_he, float* __restrict__ zacc_st)
{
    int blk = blockIdx.x;
    const ushort_t* ev; const int *cnt, *inv, *msk = nullptr;
    float* zt; int gbase, i0;
    if (blk < VV * HE_NCH) {
        int z = blk / HE_NCH, c = blk % HE_NCH;
        ev = he_ev; cnt = he_cnt; inv = he_inv;
        zt = zacc_he + z * D_OUT;
        gbase = z * PP; i0 = c * POOL_CHUNK;
    } else {
        int b2 = blk - VV * HE_NCH;
        int z = b2 / ST_NCH, c = b2 % ST_NCH;
        ev = st_ev; cnt = st_cnt; inv = st_inv;
        msk = mask;
        zt = zacc_st + z * D_OUT;
        gbase = z * MM; i0 = c * POOL_CHUNK;
    }
    int d = threadIdx.x;
    float s = 0.0f;
    bool any = false;
    #pragma unroll
    for (int i = 0; i < POOL_CHUNK; ++i) {
        int g = gbase + i0 + i;
        if (msk && msk[g] == 0) continue;
        any = true;
        int cn = cnt[g];
        const int* ip = inv + (long)g * DEG_CAP;
        float a = 0.0f;
        for (int e = 0; e < cn; ++e)
            a += bf2f(ev[(long)ip[e] * D_OUT + d]);
        float w = rsqrtf(fmaxf((float)cn, EPSF));
        float x = w * a;
        s += 0.5f * x * (1.0f + erff(x * 0.70710678118654752f));   // exact GELU
    }
    if (any || !msk) atomicAdd(&zt[d], s);
}

// ---------------- final: divide + l2norm + contrastive loss ----------------
__global__ __launch_bounds__(64) void final_kernel(const float* __restrict__ zacc_he,
                                                   const float* __restrict__ zacc_st,
                                                   const int* __restrict__ maskcnt,
                                                   float* __restrict__ out) {
    __shared__ float he[VV][D_OUT];
    __shared__ float st[VV][D_OUT];
    __shared__ float lg[VV][VV];
    __shared__ float rn_he[VV], rn_st[VV];
    int t = threadIdx.x;
    for (int i = t; i < VV * D_OUT; i += 64) {
        int v = i >> 8;
        he[v][i & 255] = zacc_he[i] / (float)PP;
        st[v][i & 255] = zacc_st[i] / (float)maskcnt[v];
    }
    __syncthreads();
    if (t < VV) {
        float s = 0.0f;
        for (int d2 = 0; d2 < D_OUT; ++d2) s += he[t][d2] * he[t][d2];
        rn_he[t] = 1.0f / fmaxf(sqrtf(s), EPSF);
    } else if (t < 2 * VV) {
        int v = t - VV; float s = 0.0f;
        for (int d2 = 0; d2 < D_OUT; ++d2) s += st[v][d2] * st[v][d2];
        rn_st[v] = 1.0f / fmaxf(sqrtf(s), EPSF);
    }
    __syncthreads();
    int v = t >> 3, w2 = t & 7;
    float dot = 0.0f;
    for (int d2 = 0; d2 < D_OUT; ++d2) dot += he[v][d2] * st[w2][d2];
    lg[v][w2] = dot * rn_he[v] * rn_st[w2] / TEMP;
    __syncthreads();
    if (t == 0) {
        float l1 = 0.0f, l2 = 0.0f;
        for (int i = 0; i < VV; ++i) {
            float mx = -1e30f;
            for (int jj = 0; jj < VV; ++jj) mx = fmaxf(mx, lg[i][jj]);
            float se = 0.0f;
            for (int jj = 0; jj < VV; ++jj) se += expf(lg[i][jj] - mx);
            l1 += lg[i][i] - (mx + logf(se));
            float mx2 = -1e30f;
            for (int jj = 0; jj < VV; ++jj) mx2 = fmaxf(mx2, lg[jj][i]);
            float se2 = 0.0f;
            for (int jj = 0; jj < VV; ++jj) se2 += expf(lg[jj][i] - mx2);
            l2 += lg[i][i] - (mx2 + logf(se2));
        }
        out[0] = 0.5f * (-(l1 / (float)VV) - (l2 / (float)VV));
    }
}

// ---------------- launch ----------------
extern "C" void kernel_launch(void* const* d_in, const int* in_sizes, int n_in,
                              void* d_out, int out_size, void* d_ws, size_t ws_size,
                              hipStream_t stream) {
    const float* F    = (const float*)d_in[0];
    const float* T    = (const float*)d_in[1];
    const float* E    = (const float*)d_in[3];
    const float* S    = (const float*)d_in[4];
    const float* W_he = (const float*)d_in[5];
    const float* W_st = (const float*)d_in[6];
    float* out = (float*)d_out;

    size_t off = 0;
    auto take = [&](size_t bytes) -> void* {
        void* p = (char*)d_ws + off;
        off += (bytes + 255) & ~(size_t)255;
        return p;
    };
    ushort_t* Fs    = (ushort_t*)take((size_t)NN * 2 * HE_DIM * 2);   // 33.5 MB
    ushort_t* Es    = (ushort_t*)take((size_t)MM * 2 * ST_DIM * 2);   // 4.2 MB
    ushort_t* Whes  = (ushort_t*)take((size_t)D_OUT * 2 * HE_DIM * 2);
    ushort_t* Wsts  = (ushort_t*)take((size_t)D_OUT * 2 * ST_DIM * 2);
    float* Xw_he    = (float*)take((size_t)NN * D_OUT * 4);           // 8 MB
    float* Xw_st    = (float*)take((size_t)MM * D_OUT * 4);           // 2 MB
    float* rnF      = (float*)take((size_t)NN * 4);
    float* rnE      = (float*)take((size_t)MM * 4);
    int*   mask     = (int*)  take((size_t)VV * MM * 4);
    int*   maskcnt  = (int*)  take((size_t)VV * 4);
    ushort_t* he_sim = (ushort_t*)take((size_t)VV * PP * PP * 2);     // 16 MB (f16)
    ushort_t* st_sim = (ushort_t*)take((size_t)MM * MM * 2);          // 8 MB (f16)
    int*   he_idx   = (int*)  take((size_t)NN * K_HG * 4);
    int*   st_idx   = (int*)  take((size_t)VV * MM * K_HG * 4);
    // zero-init region (zeroed inside prep): counts + cursors + z accumulators
    size_t zero_beg = off;
    int*   he_cnt   = (int*)  take((size_t)NN * 4);
    int*   st_cnt   = (int*)  take((size_t)VV * MM * 4);
    int*   he_cur   = (int*)  take((size_t)NN * 4);
    int*   st_cur   = (int*)  take((size_t)VV * MM * 4);
    float* zacc_he  = (float*)take((size_t)VV * D_OUT * 4);
    float* zacc_st  = (float*)take((size_t)VV * D_OUT * 4);
    size_t zero_end = off;
    int*   he_inv   = (int*)  take((size_t)NN * DEG_CAP * 4);         // 3 MB
    int*   st_inv   = (int*)  take((size_t)VV * MM * DEG_CAP * 4);    // 6 MB
    ushort_t* he_ev = (ushort_t*)take((size_t)NN * D_OUT * 2);        // 4 MB (bf16)
    ushort_t* st_ev = (ushort_t*)take((size_t)VV * MM * D_OUT * 2);   // 8 MB (bf16)

    int nZeroInts = (int)((zero_end - zero_beg) / 4);

    // split hi/lo + row norms + centroids/mask + zeroing (one launch)
    prep_kernel<<<NPREP + VV, 256, 0, stream>>>(F, E, W_he, W_st, T, S,
                                                Fs, Es, Whes, Wsts, rnF, rnE,
                                                mask, maskcnt,
                                                (int*)((char*)d_ws + zero_beg), nZeroInts);

    // all four GEMMs in one grouped launch (f16 sims, f32 projections)
    gemm_grouped<<<NB_ALL, 256, 0, stream>>>(Fs, Es, Whes, Wsts,
                                             he_sim, st_sim, Xw_he, Xw_st,
                                             rnF, rnE);

    // top-5 + degree counts (packed integer keys, 4 waves/block)
    topk_kernel<<<(NN + VV * MM) / 4, 256, 0, stream>>>(he_sim, st_sim, mask,
                                                        he_idx, st_idx, he_cnt, st_cnt);
    // per-edge values (bf16) + capacity-based inverse fill
    edge_kernel<<<NN + VV * MM, 256, 0, stream>>>(he_idx, st_idx, Xw_he, Xw_st,
                                                  he_cnt, st_cnt,
                                                  he_cur, st_cur, he_inv, st_inv,
                                                  he_ev, st_ev);
    // gather + gelu + atomic pool directly into z accumulators
    pool_gather_kernel<<<VV * HE_NCH + VV * ST_NCH, 256, 0, stream>>>(
        he_ev, st_ev, he_cnt, st_cnt, he_inv, st_inv,
        mask, zacc_he, zacc_st);
    // divide + loss
    final_kernel<<<1, 64, 0, stream>>>(zacc_he, zacc_st, maskcnt, out);
}

// Round 21
// 138.933 us; speedup vs baseline: 1.1792x; 1.0591x over previous
//
#include <hip/hip_runtime.h>
#include <hip/hip_bf16.h>
#include <hip/hip_fp16.h>
#include <math.h>

// ---------------- problem constants ----------------
#define NN      8192
#define VV      8
#define PP      1024      // N / V
#define MM      2048
#define HE_DIM  1024
#define ST_DIM  512
#define D_OUT   256
#define K_HG    5
#define RADIUS  150.0f
#define TEMP    0.07f
#define EPSF    1e-12f

#define POOL_CHUNK 4
#define HE_NCH  (PP / POOL_CHUNK)   // 256
#define ST_NCH  (MM / POOL_CHUNK)   // 512
#define DEG_CAP 96                  // max node in-degree (KNN in-degree max ~20)

// grouped-GEMM block ranges
#define HE_TRI   36                 // 8x8 upper triangle
#define ST_TRI   136                // 16x16 upper triangle
#define NB_HE    (VV * HE_TRI)      // 288
#define NB_ST    ST_TRI             // 136
#define NB_PH    ((NN / 128) * (D_OUT / 128))   // 128
#define NB_PS    ((MM / 128) * (D_OUT / 128))   // 32
#define NB_ALL   (NB_HE + NB_ST + NB_PH + NB_PS) // 584 = 8 * 73

#define NPREP   (NN + MM + 2 * D_OUT)   // rows handled by prep; +VV extra blocks

typedef __bf16 bf16x8 __attribute__((ext_vector_type(8)));
typedef float  f32x4  __attribute__((ext_vector_type(4)));
typedef unsigned short ushort_t;

typedef __attribute__((address_space(1))) void gvoid;
typedef __attribute__((address_space(3))) void svoid;
#define GLOAD16(g, l) __builtin_amdgcn_global_load_lds((gvoid*)(g), (svoid*)(l), 16, 0, 0)
#define FENCE() asm volatile("" ::: "memory")

__device__ __forceinline__ ushort_t f2bf(float x) {
    unsigned int b = __float_as_uint(x);
    return (ushort_t)((b + 0x7fffu + ((b >> 16) & 1u)) >> 16);   // RNE
}
__device__ __forceinline__ float bf2f(ushort_t h) {
    return __uint_as_float(((unsigned int)h) << 16);
}
__device__ __forceinline__ ushort_t f2h(float x) {
    return __half_as_ushort(__float2half_rn(x));
}

// ---------------- fused: split + rownorm + (centers/mask/zero in tail blocks) ----------------
__global__ __launch_bounds__(256) void prep_kernel(
    const float* __restrict__ F, const float* __restrict__ E,
    const float* __restrict__ Whe, const float* __restrict__ Wst,
    const float* __restrict__ T, const float* __restrict__ S,
    ushort_t* __restrict__ Fs, ushort_t* __restrict__ Es,
    ushort_t* __restrict__ Whes, ushort_t* __restrict__ Wsts,
    float* __restrict__ rnF, float* __restrict__ rnE,
    int* __restrict__ mask, int* __restrict__ maskcnt,
    int* __restrict__ zeroPtr, int nZeroInts)
{
    int b = blockIdx.x;
    if (b >= NPREP) {
        int v = b - NPREP;
        int per = (nZeroInts + VV - 1) / VV;
        for (int i = threadIdx.x; i < per; i += 256) {
            int idx = v * per + i;
            if (idx < nZeroInts) zeroPtr[idx] = 0;
        }
        float sx = 0.0f, sy = 0.0f;
        for (int i = threadIdx.x; i < PP; i += 256) {
            sx += T[(long)(v * PP + i) * 2 + 0];
            sy += T[(long)(v * PP + i) * 2 + 1];
        }
        __shared__ float rx[256], ry[256];
        __shared__ int   rc[256];
        rx[threadIdx.x] = sx; ry[threadIdx.x] = sy; __syncthreads();
        for (int o = 128; o > 0; o >>= 1) {
            if (threadIdx.x < o) { rx[threadIdx.x] += rx[threadIdx.x + o]; ry[threadIdx.x] += ry[threadIdx.x + o]; }
            __syncthreads();
        }
        float cx = rx[0] / (float)PP, cy = ry[0] / (float)PP;
        __syncthreads();
        int cnt = 0;
        for (int m = threadIdx.x; m < MM; m += 256) {
            float dx = cx - S[m * 2 + 0];
            float dy = cy - S[m * 2 + 1];
            int in = (sqrtf(dx * dx + dy * dy) < RADIUS) ? 1 : 0;
            mask[v * MM + m] = in;
            cnt += in;
        }
        rc[threadIdx.x] = cnt; __syncthreads();
        for (int o = 128; o > 0; o >>= 1) {
            if (threadIdx.x < o) rc[threadIdx.x] += rc[threadIdx.x + o];
            __syncthreads();
        }
        if (threadIdx.x == 0) maskcnt[v] = rc[0];
        return;
    }
    const float* src; ushort_t* dst; float* rn; int K; long row;
    if (b < NN)                    { src = F;   dst = Fs;   rn = rnF;    K = HE_DIM; row = b; }
    else if (b < NN + MM)          { src = E;   dst = Es;   rn = rnE;    K = ST_DIM; row = b - NN; }
    else if (b < NN + MM + D_OUT)  { src = Whe; dst = Whes; rn = nullptr; K = HE_DIM; row = b - NN - MM; }
    else                           { src = Wst; dst = Wsts; rn = nullptr; K = ST_DIM; row = b - NN - MM - D_OUT; }
    const float4* srow = (const float4*)(src + row * (long)K);
    ushort_t* drow = dst + row * 2L * K;
    float s = 0.0f;
    for (int j4 = threadIdx.x; j4 < (K >> 2); j4 += 256) {
        float4 x = srow[j4];
        float xs[4] = {x.x, x.y, x.z, x.w};
        ushort_t hs[4], ls[4];
        #pragma unroll
        for (int t = 0; t < 4; ++t) {
            hs[t] = f2bf(xs[t]);
            ls[t] = f2bf(xs[t] - bf2f(hs[t]));    // lo residual
            s += xs[t] * xs[t];
        }
        *(ushort4*)(drow + j4 * 4)     = make_ushort4(hs[0], hs[1], hs[2], hs[3]);
        *(ushort4*)(drow + K + j4 * 4) = make_ushort4(ls[0], ls[1], ls[2], ls[3]);
    }
    if (rn) {
        __shared__ float red[256];
        red[threadIdx.x] = s; __syncthreads();
        for (int o = 128; o > 0; o >>= 1) {
            if (threadIdx.x < o) red[threadIdx.x] += red[threadIdx.x + o];
            __syncthreads();
        }
        if (threadIdx.x == 0) rn[row] = 1.0f / fmaxf(sqrtf(red[0]), EPSF);
    }
}

// ---------------- grouped split-bf16 MFMA GEMM ----------------
// Uniform pipeline: per segment pass, 3-buf {A,B} 16 KB bufs, depth-2 prefetch,
// counted vmcnt. 48 KB LDS -> 3 blocks/CU. Longest blocks (proj, 3 passes)
// dispatched first via the XCD map.
__global__ __launch_bounds__(256) void gemm_grouped(
    const ushort_t* __restrict__ Fs, const ushort_t* __restrict__ Es,
    const ushort_t* __restrict__ Whes, const ushort_t* __restrict__ Wsts,
    ushort_t* __restrict__ he_sim, ushort_t* __restrict__ st_sim,
    float* __restrict__ Xw_he, float* __restrict__ Xw_st,
    const float* __restrict__ rnF, const float* __restrict__ rnE)
{
    // XCD map: per-xcd order = proj (longest, first), ST, then HE (own-region tiles).
    int bid = blockIdx.x;
    int xcd = bid & 7, j = bid >> 3;    // j in [0,73); 584 = 8*73 bijective
    int id;
    if (j < 20)      id = NB_HE + (17 + j) * 8 + xcd;    // proj: rest-rows 17..36
    else if (j < 37) id = NB_HE + (j - 20) * 8 + xcd;    // ST:   rest-rows 0..16
    else             id = xcd * HE_TRI + (j - 37);       // HE:   own region

    const ushort_t *A, *B; ushort_t *Ch = nullptr; float *Cf = nullptr;
    const float *rA = nullptr, *rB = nullptr;
    int K, Nn, bm, bn, sym, nseg;
    if (id < NB_HE) {
        int z = id / HE_TRI, t = id - z * HE_TRI;
        int i = 0;
        while (t >= 8 - i) { t -= 8 - i; ++i; }
        bm = i * 128; bn = (i + t) * 128;
        A = B = Fs + (long)z * PP * 2 * HE_DIM;
        Ch = he_sim + (long)z * PP * PP;
        rA = rB = rnF + z * PP;
        K = HE_DIM; Nn = PP; sym = 1; nseg = 1;
    } else if (id < NB_HE + NB_ST) {
        int t = id - NB_HE;
        int i = 0;
        while (t >= 16 - i) { t -= 16 - i; ++i; }
        bm = i * 128; bn = (i + t) * 128;
        A = B = Es; Ch = st_sim; rA = rB = rnE;
        K = ST_DIM; Nn = MM; sym = 1; nseg = 2;
    } else if (id < NB_HE + NB_ST + NB_PH) {
        int t = id - (NB_HE + NB_ST);
        bm = (t >> 1) * 128; bn = (t & 1) * 128;
        A = Fs; B = Whes; Cf = Xw_he;
        K = HE_DIM; Nn = D_OUT; sym = 0; nseg = 3;
    } else {
        int t = id - (NB_HE + NB_ST + NB_PH);
        bm = (t >> 1) * 128; bn = (t & 1) * 128;
        A = Es; B = Wsts; Cf = Xw_st;
        K = ST_DIM; Nn = D_OUT; sym = 0; nseg = 3;
    }

    __shared__ ushort_t sm[24576];   // 48 KB: 3 bufs x {A 8KB, B 8KB}
    char* const smb = (char*)&sm[0];
    const int tid  = threadIdx.x;
    const int lane = tid & 63, wave = tid >> 6;
    const int wr = wave >> 1, wc = wave & 1;
    const int fr = lane & 15, fg = lane >> 4;

    const long lda = 2L * K;
    const int srow = wave * 16 + (lane >> 2);
    const int scol = (((lane & 3) ^ ((srow >> 1) & 3)) * 8);  // pre-swizzled src col

    f32x4 acc[4][4] = {};

    auto roA = [&](int m) { int row = wr * 64 + m * 16 + fr;
                            return row * 64 + ((fg ^ ((row >> 1) & 3)) * 16); };
    auto roB = [&](int n) { int row = wc * 64 + n * 16 + fr;
                            return row * 64 + ((fg ^ ((row >> 1) & 3)) * 16); };

    #pragma unroll 1
    for (int p = 0; p < nseg; ++p) {
        const long aoff = (p == 1) ? (long)K : 0;   // pass 1: A-lo x B-hi
        const long boff = (p == 2) ? (long)K : 0;   // pass 2: A-hi x B-lo
        auto STG = [&](int kk, int b) {
            const ushort_t* ga = A + (long)(bm + srow) * lda + aoff + kk + scol;
            const ushort_t* gb = B + (long)(bn + srow) * lda + boff + kk + scol;
            char* AT = smb + b * 16384 + wave * 1024;
            char* BT = AT + 8192;
            GLOAD16(ga, AT); GLOAD16(ga + 64 * lda, AT + 4096);
            GLOAD16(gb, BT); GLOAD16(gb + 64 * lda, BT + 4096);
        };
        STG(0, 0); STG(32, 1);
        int buf = 0;
        for (int kk = 0; kk < K; kk += 32) {
            if (kk + 64 < K) {
                STG(kk + 64, buf == 0 ? 2 : buf - 1);
                asm volatile("s_waitcnt vmcnt(8)" ::: "memory");
            } else if (kk + 32 < K) {
                asm volatile("s_waitcnt vmcnt(4)" ::: "memory");
            } else {
                asm volatile("s_waitcnt vmcnt(0)" ::: "memory");
            }
            FENCE(); __builtin_amdgcn_s_barrier(); FENCE();
            const char* ab = smb + buf * 16384;
            bf16x8 a4[4], b4[4];
            #pragma unroll
            for (int m = 0; m < 4; ++m) a4[m] = *(const bf16x8*)(ab + roA(m));
            #pragma unroll
            for (int n = 0; n < 4; ++n) b4[n] = *(const bf16x8*)(ab + 8192 + roB(n));
            #pragma unroll
            for (int m = 0; m < 4; ++m)
                #pragma unroll
                for (int n = 0; n < 4; ++n)
                    acc[m][n] = __builtin_amdgcn_mfma_f32_16x16x32_bf16(a4[m], b4[n], acc[m][n], 0, 0, 0);
            FENCE(); __builtin_amdgcn_s_barrier(); FENCE();
            buf = (buf == 2) ? 0 : buf + 1;
        }
    }

    if (sym) {
        // ---- direct store (f16) ----
        #pragma unroll
        for (int m = 0; m < 4; ++m) {
            #pragma unroll
            for (int r = 0; r < 4; ++r) {
                int row = bm + wr * 64 + m * 16 + fg * 4 + r;
                float ra = rA[row];
                #pragma unroll
                for (int n = 0; n < 4; ++n) {
                    int col = bn + wc * 64 + n * 16 + fr;
                    Ch[(long)row * Nn + col] = f2h(acc[m][n][r] * ra * rB[col]);
                }
            }
        }
        if (bn > bm) {
            // ---- mirror store via LDS transpose (f16 out); 33.8 KB < 48 KB ----
            float* tbuf = (float*)smb;
            #pragma unroll
            for (int h = 0; h < 2; ++h) {
                __syncthreads();
                if (wc == h) {
                    #pragma unroll
                    for (int m = 0; m < 4; ++m)
                        #pragma unroll
                        for (int r = 0; r < 4; ++r) {
                            int row = wr * 64 + m * 16 + fg * 4 + r;
                            float ra = rA[bm + row];
                            #pragma unroll
                            for (int n = 0; n < 4; ++n) {
                                int cloc = n * 16 + fr;
                                float rb = rB[bn + h * 64 + cloc];
                                tbuf[cloc * 132 + row] = acc[m][n][r] * ra * rb;
                            }
                        }
                }
                __syncthreads();
                #pragma unroll
                for (int q = 0; q < 8; ++q) {
                    int fi = (q * 256 + tid) * 4;    // 0..8191
                    int rp = fi >> 7;                // transposed row 0..63
                    int cp = fi & 127;               // col 0..127 (step 4)
                    ushort4 val = make_ushort4(
                        f2h(tbuf[rp * 132 + cp]),     f2h(tbuf[rp * 132 + cp + 1]),
                        f2h(tbuf[rp * 132 + cp + 2]), f2h(tbuf[rp * 132 + cp + 3]));
                    *(ushort4*)&Ch[(long)(bn + h * 64 + rp) * Nn + bm + cp] = val;
                }
            }
        }
    } else {
        // ---- direct store (f32, projections) ----
        #pragma unroll
        for (int m = 0; m < 4; ++m) {
            #pragma unroll
            for (int r = 0; r < 4; ++r) {
                int row = bm + wr * 64 + m * 16 + fg * 4 + r;
                #pragma unroll
                for (int n = 0; n < 4; ++n) {
                    int col = bn + wc * 64 + n * 16 + fr;
                    Cf[(long)row * Nn + col] = acc[m][n][r];
                }
            }
        }
    }
}

// ---------------- merged top-5 per row + degree counts (packed-key, 4 waves/block) ----------------
__global__ __launch_bounds__(256) void topk_kernel(
    const ushort_t* __restrict__ he_sim, const ushort_t* __restrict__ st_sim,
    const int* __restrict__ mask,
    int* __restrict__ he_idx, int* __restrict__ st_idx,
    int* __restrict__ he_cnt, int* __restrict__ st_cnt)
{
    int gb = blockIdx.x * 4 + (threadIdx.x >> 6);
    int lane = threadIdx.x & 63;
    unsigned k0 = 0, k1 = 0, k2 = 0, k3 = 0, k4 = 0;
    int* outIdx; int* cntp;

    auto skey = [](unsigned h) -> unsigned {
        unsigned s = h >> 15;
        return h ^ (((0u - s) | 0x8000u) & 0xFFFFu);
    };
    auto insk = [&](unsigned key) {
        bool c0 = key > k0, c1 = key > k1, c2 = key > k2, c3 = key > k3, c4 = key > k4;
        k4 = c4 ? (c3 ? k3 : key) : k4;
        k3 = c3 ? (c2 ? k2 : key) : k3;
        k2 = c2 ? (c1 ? k1 : key) : k2;
        k1 = c1 ? (c0 ? k0 : key) : k1;
        k0 = c0 ? key : k0;
    };

    if (gb < NN) {
        int z = gb >> 10;
        const uint4* row8 = (const uint4*)(he_sim + (long)z * PP * PP + (long)(gb & (PP - 1)) * PP);
        outIdx = he_idx + (long)gb * K_HG;
        cntp = he_cnt + z * PP;
        #pragma unroll
        for (int it = 0; it < (PP / 8) / 64; ++it) {      // 2 iters
            int j8 = it * 64 + lane;
            uint4 u = row8[j8];
            unsigned inv = 0xFFFFu - (unsigned)(j8 * 8);
            insk((skey(u.x & 0xFFFFu) << 16) | inv);
            insk((skey(u.x >> 16)     << 16) | (inv - 1));
            insk((skey(u.y & 0xFFFFu) << 16) | (inv - 2));
            insk((skey(u.y >> 16)     << 16) | (inv - 3));
            insk((skey(u.z & 0xFFFFu) << 16) | (inv - 4));
            insk((skey(u.z >> 16)     << 16) | (inv - 5));
            insk((skey(u.w & 0xFFFFu) << 16) | (inv - 6));
            insk((skey(u.w >> 16)     << 16) | (inv - 7));
        }
    } else {
        int g2 = gb - NN;
        int z = g2 >> 11, e = g2 & (MM - 1);
        const int* mk = mask + (long)z * MM;
        outIdx = st_idx + (long)g2 * K_HG;
        cntp = st_cnt + z * MM;
        if (mk[e] == 0) {
            if (lane == 0) {
                #pragma unroll
                for (int r = 0; r < K_HG; ++r) outIdx[r] = -1;
            }
            return;
        }
        const uint4* row8 = (const uint4*)(st_sim + (long)e * MM);
        const int4*  mk4  = (const int4*)mk;
        #pragma unroll
        for (int it = 0; it < (MM / 8) / 64; ++it) {      // 4 iters
            int j8 = it * 64 + lane;
            uint4 u = row8[j8];
            int4 ma = mk4[2 * j8], mb = mk4[2 * j8 + 1];
            unsigned inv = 0xFFFFu - (unsigned)(j8 * 8);
            insk(ma.x ? ((skey(u.x & 0xFFFFu) << 16) | inv)       : 0u);
            insk(ma.y ? ((skey(u.x >> 16)     << 16) | (inv - 1)) : 0u);
            insk(ma.z ? ((skey(u.y & 0xFFFFu) << 16) | (inv - 2)) : 0u);
            insk(ma.w ? ((skey(u.y >> 16)     << 16) | (inv - 3)) : 0u);
            insk(mb.x ? ((skey(u.z & 0xFFFFu) << 16) | (inv - 4)) : 0u);
            insk(mb.y ? ((skey(u.z >> 16)     << 16) | (inv - 5)) : 0u);
            insk(mb.z ? ((skey(u.w & 0xFFFFu) << 16) | (inv - 6)) : 0u);
            insk(mb.w ? ((skey(u.w >> 16)     << 16) | (inv - 7)) : 0u);
        }
    }

    // 5 rounds of wave max merge (keys unique -> exact pop)
    #pragma unroll
    for (int r = 0; r < K_HG; ++r) {
        unsigned bk = k0;
        for (int o = 32; o > 0; o >>= 1) {
            unsigned ok = (unsigned)__shfl_xor((int)bk, o, 64);
            bk = ok > bk ? ok : bk;
        }
        if (lane == 0) {
            int bi = (int)(0xFFFFu - (bk & 0xFFFFu));
            outIdx[r] = bi;
            atomicAdd(&cntp[bi], 1);
        }
        if (k0 == bk) {
            k0 = k1; k1 = k2; k2 = k3; k3 = k4; k4 = 0;
        }
    }
}

// ---------------- merged per-edge value (bf16 out) + capacity-CSR fill ----------------
__global__ __launch_bounds__(256) void edge_kernel(
    const int* __restrict__ he_idx, const int* __restrict__ st_idx,
    const float* __restrict__ Xw_he, const float* __restrict__ Xw_st,
    const int* __restrict__ he_cnt, const int* __restrict__ st_cnt,
    int* __restrict__ he_cur, int* __restrict__ st_cur,
    int* __restrict__ he_inv, int* __restrict__ st_inv,
    ushort_t* __restrict__ he_ev, ushort_t* __restrict__ st_ev)
{
    int b = blockIdx.x;
    const int *idx, *cnt; const float* Xw;
    int *cur, *inv; ushort_t* ev;
    int ge, gbase, rowsPerZ; long xwBase;
    if (b < NN) {
        ge = b; int z = ge >> 10;
        idx = he_idx; Xw = Xw_he; cnt = he_cnt;
        cur = he_cur; inv = he_inv; ev = he_ev;
        rowsPerZ = PP; gbase = z * PP; xwBase = (long)z * PP;
    } else {
        ge = b - NN; int z = ge >> 11;
        idx = st_idx; Xw = Xw_st; cnt = st_cnt;
        cur = st_cur; inv = st_inv; ev = st_ev;
        rowsPerZ = MM; gbase = z * MM; xwBase = 0;
    }
    int mm[K_HG];
    #pragma unroll
    for (int k = 0; k < K_HG; ++k) mm[k] = idx[(long)ge * K_HG + k];
    if (mm[0] < 0) return;   // masked-out ST edge
    int d = threadIdx.x;
    float val = 0.0f;
    #pragma unroll
    for (int k = 0; k < K_HG; ++k) {
        int m = mm[k];
        if (m < 0 || m >= rowsPerZ) continue;
        float w = rsqrtf(fmaxf((float)cnt[gbase + m], EPSF));
        val += w * Xw[(xwBase + m) * D_OUT + d];
    }
    ev[(long)ge * D_OUT + d] = f2bf(val * (1.0f / (float)K_HG));
    if (d < K_HG) {
        int m = mm[d];
        if (m >= 0 && m < rowsPerZ) {
            int g = gbase + m;
            int pos = atomicAdd(&cur[g], 1);
            if (pos < DEG_CAP) inv[(long)g * DEG_CAP + pos] = ge;
        }
    }
}

// ---------------- node gather + Dv^-1/2 + GELU + atomic pool into z ----------------
__global__ __launch_bounds__(256) void pool_gather_kernel(
    const ushort_t* __restrict__ he_ev, const ushort_t* __restrict__ st_ev,
    const int* __restrict__ he_cnt, const int* __restrict__ st_cnt,
    const int* __restrict__ he_inv, const int* __restrict__ st_inv,
    const int* __restrict__ mask,
    float* __restrict__ zacc_he, float* __restrict__ zacc_st)
{
    int blk = blockIdx.x;
    const ushort_t* ev; const int *cnt, *inv, *msk = nullptr;
    float* zt; int gbase, i0;
    if (blk < VV * HE_NCH) {
        int z = blk / HE_NCH, c = blk % HE_NCH;
        ev = he_ev; cnt = he_cnt; inv = he_inv;
        zt = zacc_he + z * D_OUT;
        gbase = z * PP; i0 = c * POOL_CHUNK;
    } else {
        int b2 = blk - VV * HE_NCH;
        int z = b2 / ST_NCH, c = b2 % ST_NCH;
        ev = st_ev; cnt = st_cnt; inv = st_inv;
        msk = mask;
        zt = zacc_st + z * D_OUT;
        gbase = z * MM; i0 = c * POOL_CHUNK;
    }
    int d = threadIdx.x;
    float s = 0.0f;
    bool any = false;
    #pragma unroll
    for (int i = 0; i < POOL_CHUNK; ++i) {
        int g = gbase + i0 + i;
        if (msk && msk[g] == 0) continue;
        any = true;
        int cn = cnt[g];
        const int* ip = inv + (long)g * DEG_CAP;
        float a = 0.0f;
        for (int e = 0; e < cn; ++e)
            a += bf2f(ev[(long)ip[e] * D_OUT + d]);
        float w = rsqrtf(fmaxf((float)cn, EPSF));
        float x = w * a;
        s += 0.5f * x * (1.0f + erff(x * 0.70710678118654752f));   // exact GELU
    }
    if (any || !msk) atomicAdd(&zt[d], s);
}

// ---------------- final: divide + l2norm + contrastive loss ----------------
__global__ __launch_bounds__(64) void final_kernel(const float* __restrict__ zacc_he,
                                                   const float* __restrict__ zacc_st,
                                                   const int* __restrict__ maskcnt,
                                                   float* __restrict__ out) {
    __shared__ float he[VV][D_OUT];
    __shared__ float st[VV][D_OUT];
    __shared__ float lg[VV][VV];
    __shared__ float rn_he[VV], rn_st[VV];
    int t = threadIdx.x;
    for (int i = t; i < VV * D_OUT; i += 64) {
        int v = i >> 8;
        he[v][i & 255] = zacc_he[i] / (float)PP;
        st[v][i & 255] = zacc_st[i] / (float)maskcnt[v];
    }
    __syncthreads();
    if (t < VV) {
        float s = 0.0f;
        for (int d2 = 0; d2 < D_OUT; ++d2) s += he[t][d2] * he[t][d2];
        rn_he[t] = 1.0f / fmaxf(sqrtf(s), EPSF);
    } else if (t < 2 * VV) {
        int v = t - VV; float s = 0.0f;
        for (int d2 = 0; d2 < D_OUT; ++d2) s += st[v][d2] * st[v][d2];
        rn_st[v] = 1.0f / fmaxf(sqrtf(s), EPSF);
    }
    __syncthreads();
    int v = t >> 3, w2 = t & 7;
    float dot = 0.0f;
    for (int d2 = 0; d2 < D_OUT; ++d2) dot += he[v][d2] * st[w2][d2];
    lg[v][w2] = dot * rn_he[v] * rn_st[w2] / TEMP;
    __syncthreads();
    if (t == 0) {
        float l1 = 0.0f, l2 = 0.0f;
        for (int i = 0; i < VV; ++i) {
            float mx = -1e30f;
            for (int jj = 0; jj < VV; ++jj) mx = fmaxf(mx, lg[i][jj]);
            float se = 0.0f;
            for (int jj = 0; jj < VV; ++jj) se += expf(lg[i][jj] - mx);
            l1 += lg[i][i] - (mx + logf(se));
            float mx2 = -1e30f;
            for (int jj = 0; jj < VV; ++jj) mx2 = fmaxf(mx2, lg[jj][i]);
            float se2 = 0.0f;
            for (int jj = 0; jj < VV; ++jj) se2 += expf(lg[jj][i] - mx2);
            l2 += lg[i][i] - (mx2 + logf(se2));
        }
        out[0] = 0.5f * (-(l1 / (float)VV) - (l2 / (float)VV));
    }
}

// ---------------- launch ----------------
extern "C" void kernel_launch(void* const* d_in, const int* in_sizes, int n_in,
                              void* d_out, int out_size, void* d_ws, size_t ws_size,
                              hipStream_t stream) {
    const float* F    = (const float*)d_in[0];
    const float* T    = (const float*)d_in[1];
    const float* E    = (const float*)d_in[3];
    const float* S    = (const float*)d_in[4];
    const float* W_he = (const float*)d_in[5];
    const float* W_st = (const float*)d_in[6];
    float* out = (float*)d_out;

    size_t off = 0;
    auto take = [&](size_t bytes) -> void* {
        void* p = (char*)d_ws + off;
        off += (bytes + 255) & ~(size_t)255;
        return p;
    };
    ushort_t* Fs    = (ushort_t*)take((size_t)NN * 2 * HE_DIM * 2);   // 33.5 MB
    ushort_t* Es    = (ushort_t*)take((size_t)MM * 2 * ST_DIM * 2);   // 4.2 MB
    ushort_t* Whes  = (ushort_t*)take((size_t)D_OUT * 2 * HE_DIM * 2);
    ushort_t* Wsts  = (ushort_t*)take((size_t)D_OUT * 2 * ST_DIM * 2);
    float* Xw_he    = (float*)take((size_t)NN * D_OUT * 4);           // 8 MB
    float* Xw_st    = (float*)take((size_t)MM * D_OUT * 4);           // 2 MB
    float* rnF      = (float*)take((size_t)NN * 4);
    float* rnE      = (float*)take((size_t)MM * 4);
    int*   mask     = (int*)  take((size_t)VV * MM * 4);
    int*   maskcnt  = (int*)  take((size_t)VV * 4);
    ushort_t* he_sim = (ushort_t*)take((size_t)VV * PP * PP * 2);     // 16 MB (f16)
    ushort_t* st_sim = (ushort_t*)take((size_t)MM * MM * 2);          // 8 MB (f16)
    int*   he_idx   = (int*)  take((size_t)NN * K_HG * 4);
    int*   st_idx   = (int*)  take((size_t)VV * MM * K_HG * 4);
    // zero-init region (zeroed inside prep): counts + cursors + z accumulators
    size_t zero_beg = off;
    int*   he_cnt   = (int*)  take((size_t)NN * 4);
    int*   st_cnt   = (int*)  take((size_t)VV * MM * 4);
    int*   he_cur   = (int*)  take((size_t)NN * 4);
    int*   st_cur   = (int*)  take((size_t)VV * MM * 4);
    float* zacc_he  = (float*)take((size_t)VV * D_OUT * 4);
    float* zacc_st  = (float*)take((size_t)VV * D_OUT * 4);
    size_t zero_end = off;
    int*   he_inv   = (int*)  take((size_t)NN * DEG_CAP * 4);         // 3 MB
    int*   st_inv   = (int*)  take((size_t)VV * MM * DEG_CAP * 4);    // 6 MB
    ushort_t* he_ev = (ushort_t*)take((size_t)NN * D_OUT * 2);        // 4 MB (bf16)
    ushort_t* st_ev = (ushort_t*)take((size_t)VV * MM * D_OUT * 2);   // 8 MB (bf16)

    int nZeroInts = (int)((zero_end - zero_beg) / 4);

    // split hi/lo + row norms + centroids/mask + zeroing (one launch)
    prep_kernel<<<NPREP + VV, 256, 0, stream>>>(F, E, W_he, W_st, T, S,
                                                Fs, Es, Whes, Wsts, rnF, rnE,
                                                mask, maskcnt,
                                                (int*)((char*)d_ws + zero_beg), nZeroInts);

    // all four GEMMs in one grouped launch (uniform depth-2, 48 KB LDS)
    gemm_grouped<<<NB_ALL, 256, 0, stream>>>(Fs, Es, Whes, Wsts,
                                             he_sim, st_sim, Xw_he, Xw_st,
                                             rnF, rnE);

    // top-5 + degree counts (packed integer keys, 4 waves/block)
    topk_kernel<<<(NN + VV * MM) / 4, 256, 0, stream>>>(he_sim, st_sim, mask,
                                                        he_idx, st_idx, he_cnt, st_cnt);
    // per-edge values (bf16) + capacity-based inverse fill
    edge_kernel<<<NN + VV * MM, 256, 0, stream>>>(he_idx, st_idx, Xw_he, Xw_st,
                                                  he_cnt, st_cnt,
                                                  he_cur, st_cur, he_inv, st_inv,
                                                  he_ev, st_ev);
    // gather + gelu + atomic pool directly into z accumulators
    pool_gather_kernel<<<VV * HE_NCH + VV * ST_NCH, 256, 0, stream>>>(
        he_ev, st_ev, he_cnt, st_cnt, he_inv, st_inv,
        mask, zacc_he, zacc_st);
    // divide + loss
    final_kernel<<<1, 64, 0, stream>>>(zacc_he, zacc_st, maskcnt, out);
}

// Round 22
// 130.747 us; speedup vs baseline: 1.2530x; 1.0626x over previous
//
#include <hip/hip_runtime.h>
#include <hip/hip_bf16.h>
#include <hip/hip_fp16.h>
#include <math.h>

// ---------------- problem constants ----------------
#define NN      8192
#define VV      8
#define PP      1024      // N / V
#define MM      2048
#define HE_DIM  1024
#define ST_DIM  512
#define D_OUT   256
#define K_HG    5
#define RADIUS  150.0f
#define TEMP    0.07f
#define EPSF    1e-12f

#define POOL_CHUNK 4
#define HE_NCH  (PP / POOL_CHUNK)   // 256
#define ST_NCH  (MM / POOL_CHUNK)   // 512
#define DEG_CAP 96                  // max node in-degree (KNN in-degree max ~20)

// grouped-GEMM block ranges
#define HE_TRI   36                 // 8x8 upper triangle
#define ST_TRI   136                // 16x16 upper triangle
#define NB_HE    (VV * HE_TRI)      // 288
#define NB_ST    ST_TRI             // 136
#define NB_PH    ((NN / 128) * (D_OUT / 128))   // 128
#define NB_PS    ((MM / 128) * (D_OUT / 128))   // 32
#define NB_ALL   (NB_HE + NB_ST + NB_PH + NB_PS) // 584 = 8 * 73

#define NPREP   (NN + MM + 2 * D_OUT)   // rows handled by prep; +VV extra blocks

typedef __bf16 bf16x8 __attribute__((ext_vector_type(8)));
typedef float  f32x4  __attribute__((ext_vector_type(4)));
typedef unsigned short ushort_t;

typedef __attribute__((address_space(1))) void gvoid;
typedef __attribute__((address_space(3))) void svoid;
#define GLOAD16(g, l) __builtin_amdgcn_global_load_lds((gvoid*)(g), (svoid*)(l), 16, 0, 0)
#define FENCE() asm volatile("" ::: "memory")

__device__ __forceinline__ ushort_t f2bf(float x) {
    unsigned int b = __float_as_uint(x);
    return (ushort_t)((b + 0x7fffu + ((b >> 16) & 1u)) >> 16);   // RNE
}
__device__ __forceinline__ float bf2f(ushort_t h) {
    return __uint_as_float(((unsigned int)h) << 16);
}
__device__ __forceinline__ ushort_t f2h(float x) {
    return __half_as_ushort(__float2half_rn(x));
}

// ---------------- fused: split + rownorm + (centers/mask/zero in tail blocks) ----------------
__global__ __launch_bounds__(256) void prep_kernel(
    const float* __restrict__ F, const float* __restrict__ E,
    const float* __restrict__ Whe, const float* __restrict__ Wst,
    const float* __restrict__ T, const float* __restrict__ S,
    ushort_t* __restrict__ Fs, ushort_t* __restrict__ Es,
    ushort_t* __restrict__ Whes, ushort_t* __restrict__ Wsts,
    float* __restrict__ rnF, float* __restrict__ rnE,
    int* __restrict__ mask, int* __restrict__ maskcnt,
    int* __restrict__ zeroPtr, int nZeroInts)
{
    int b = blockIdx.x;
    if (b >= NPREP) {
        int v = b - NPREP;
        int per = (nZeroInts + VV - 1) / VV;
        for (int i = threadIdx.x; i < per; i += 256) {
            int idx = v * per + i;
            if (idx < nZeroInts) zeroPtr[idx] = 0;
        }
        float sx = 0.0f, sy = 0.0f;
        for (int i = threadIdx.x; i < PP; i += 256) {
            sx += T[(long)(v * PP + i) * 2 + 0];
            sy += T[(long)(v * PP + i) * 2 + 1];
        }
        __shared__ float rx[256], ry[256];
        __shared__ int   rc[256];
        rx[threadIdx.x] = sx; ry[threadIdx.x] = sy; __syncthreads();
        for (int o = 128; o > 0; o >>= 1) {
            if (threadIdx.x < o) { rx[threadIdx.x] += rx[threadIdx.x + o]; ry[threadIdx.x] += ry[threadIdx.x + o]; }
            __syncthreads();
        }
        float cx = rx[0] / (float)PP, cy = ry[0] / (float)PP;
        __syncthreads();
        int cnt = 0;
        for (int m = threadIdx.x; m < MM; m += 256) {
            float dx = cx - S[m * 2 + 0];
            float dy = cy - S[m * 2 + 1];
            int in = (sqrtf(dx * dx + dy * dy) < RADIUS) ? 1 : 0;
            mask[v * MM + m] = in;
            cnt += in;
        }
        rc[threadIdx.x] = cnt; __syncthreads();
        for (int o = 128; o > 0; o >>= 1) {
            if (threadIdx.x < o) rc[threadIdx.x] += rc[threadIdx.x + o];
            __syncthreads();
        }
        if (threadIdx.x == 0) maskcnt[v] = rc[0];
        return;
    }
    const float* src; ushort_t* dst; float* rn; int K; long row;
    if (b < NN)                    { src = F;   dst = Fs;   rn = rnF;    K = HE_DIM; row = b; }
    else if (b < NN + MM)          { src = E;   dst = Es;   rn = rnE;    K = ST_DIM; row = b - NN; }
    else if (b < NN + MM + D_OUT)  { src = Whe; dst = Whes; rn = nullptr; K = HE_DIM; row = b - NN - MM; }
    else                           { src = Wst; dst = Wsts; rn = nullptr; K = ST_DIM; row = b - NN - MM - D_OUT; }
    const float4* srow = (const float4*)(src + row * (long)K);
    ushort_t* drow = dst + row * 2L * K;
    float s = 0.0f;
    for (int j4 = threadIdx.x; j4 < (K >> 2); j4 += 256) {
        float4 x = srow[j4];
        float xs[4] = {x.x, x.y, x.z, x.w};
        ushort_t hs[4], ls[4];
        #pragma unroll
        for (int t = 0; t < 4; ++t) {
            hs[t] = f2bf(xs[t]);
            ls[t] = f2bf(xs[t] - bf2f(hs[t]));    // lo residual
            s += xs[t] * xs[t];
        }
        *(ushort4*)(drow + j4 * 4)     = make_ushort4(hs[0], hs[1], hs[2], hs[3]);
        *(ushort4*)(drow + K + j4 * 4) = make_ushort4(ls[0], ls[1], ls[2], ls[3]);
    }
    if (rn) {
        __shared__ float red[256];
        red[threadIdx.x] = s; __syncthreads();
        for (int o = 128; o > 0; o >>= 1) {
            if (threadIdx.x < o) red[threadIdx.x] += red[threadIdx.x + o];
            __syncthreads();
        }
        if (threadIdx.x == 0) rn[row] = 1.0f / fmaxf(sqrtf(red[0]), EPSF);
    }
}

// ---------------- grouped split-bf16 MFMA GEMM ----------------
// Uniform pipeline: per segment pass, 3-buf {A,B} 16 KB bufs, depth-2 prefetch,
// counted vmcnt. 48 KB LDS -> 3 blocks/CU.
// Passes: HE Gram 1 (hi*hi), ST Gram 1 (hi*hi), proj 2 (A*Bh full-A precision).
__global__ __launch_bounds__(256) void gemm_grouped(
    const ushort_t* __restrict__ Fs, const ushort_t* __restrict__ Es,
    const ushort_t* __restrict__ Whes, const ushort_t* __restrict__ Wsts,
    ushort_t* __restrict__ he_sim, ushort_t* __restrict__ st_sim,
    float* __restrict__ Xw_he, float* __restrict__ Xw_st,
    const float* __restrict__ rnF, const float* __restrict__ rnE)
{
    // XCD map: per-xcd order = proj (longest, first), ST, then HE (own-region tiles).
    int bid = blockIdx.x;
    int xcd = bid & 7, j = bid >> 3;    // j in [0,73); 584 = 8*73 bijective
    int id;
    if (j < 20)      id = NB_HE + (17 + j) * 8 + xcd;    // proj: rest-rows 17..36
    else if (j < 37) id = NB_HE + (j - 20) * 8 + xcd;    // ST:   rest-rows 0..16
    else             id = xcd * HE_TRI + (j - 37);       // HE:   own region

    const ushort_t *A, *B; ushort_t *Ch = nullptr; float *Cf = nullptr;
    const float *rA = nullptr, *rB = nullptr;
    int K, Nn, bm, bn, sym, nseg;
    if (id < NB_HE) {
        int z = id / HE_TRI, t = id - z * HE_TRI;
        int i = 0;
        while (t >= 8 - i) { t -= 8 - i; ++i; }
        bm = i * 128; bn = (i + t) * 128;
        A = B = Fs + (long)z * PP * 2 * HE_DIM;
        Ch = he_sim + (long)z * PP * PP;
        rA = rB = rnF + z * PP;
        K = HE_DIM; Nn = PP; sym = 1; nseg = 1;
    } else if (id < NB_HE + NB_ST) {
        int t = id - NB_HE;
        int i = 0;
        while (t >= 16 - i) { t -= 16 - i; ++i; }
        bm = i * 128; bn = (i + t) * 128;
        A = B = Es; Ch = st_sim; rA = rB = rnE;
        K = ST_DIM; Nn = MM; sym = 1; nseg = 1;
    } else if (id < NB_HE + NB_ST + NB_PH) {
        int t = id - (NB_HE + NB_ST);
        bm = (t >> 1) * 128; bn = (t & 1) * 128;
        A = Fs; B = Whes; Cf = Xw_he;
        K = HE_DIM; Nn = D_OUT; sym = 0; nseg = 2;
    } else {
        int t = id - (NB_HE + NB_ST + NB_PH);
        bm = (t >> 1) * 128; bn = (t & 1) * 128;
        A = Es; B = Wsts; Cf = Xw_st;
        K = ST_DIM; Nn = D_OUT; sym = 0; nseg = 2;
    }

    __shared__ ushort_t sm[24576];   // 48 KB: 3 bufs x {A 8KB, B 8KB}
    char* const smb = (char*)&sm[0];
    const int tid  = threadIdx.x;
    const int lane = tid & 63, wave = tid >> 6;
    const int wr = wave >> 1, wc = wave & 1;
    const int fr = lane & 15, fg = lane >> 4;

    const long lda = 2L * K;
    const int srow = wave * 16 + (lane >> 2);
    const int scol = (((lane & 3) ^ ((srow >> 1) & 3)) * 8);  // pre-swizzled src col

    f32x4 acc[4][4] = {};

    auto roA = [&](int m) { int row = wr * 64 + m * 16 + fr;
                            return row * 64 + ((fg ^ ((row >> 1) & 3)) * 16); };
    auto roB = [&](int n) { int row = wc * 64 + n * 16 + fr;
                            return row * 64 + ((fg ^ ((row >> 1) & 3)) * 16); };

    #pragma unroll 1
    for (int p = 0; p < nseg; ++p) {
        const long aoff = (p == 1) ? (long)K : 0;   // pass 1: A-lo x B-hi
        const long boff = (p == 2) ? (long)K : 0;   // pass 2: A-hi x B-lo (unused now)
        auto STG = [&](int kk, int b) {
            const ushort_t* ga = A + (long)(bm + srow) * lda + aoff + kk + scol;
            const ushort_t* gb = B + (long)(bn + srow) * lda + boff + kk + scol;
            char* AT = smb + b * 16384 + wave * 1024;
            char* BT = AT + 8192;
            GLOAD16(ga, AT); GLOAD16(ga + 64 * lda, AT + 4096);
            GLOAD16(gb, BT); GLOAD16(gb + 64 * lda, BT + 4096);
        };
        STG(0, 0); STG(32, 1);
        int buf = 0;
        for (int kk = 0; kk < K; kk += 32) {
            if (kk + 64 < K) {
                STG(kk + 64, buf == 0 ? 2 : buf - 1);
                asm volatile("s_waitcnt vmcnt(8)" ::: "memory");
            } else if (kk + 32 < K) {
                asm volatile("s_waitcnt vmcnt(4)" ::: "memory");
            } else {
                asm volatile("s_waitcnt vmcnt(0)" ::: "memory");
            }
            FENCE(); __builtin_amdgcn_s_barrier(); FENCE();
            const char* ab = smb + buf * 16384;
            bf16x8 a4[4], b4[4];
            #pragma unroll
            for (int m = 0; m < 4; ++m) a4[m] = *(const bf16x8*)(ab + roA(m));
            #pragma unroll
            for (int n = 0; n < 4; ++n) b4[n] = *(const bf16x8*)(ab + 8192 + roB(n));
            #pragma unroll
            for (int m = 0; m < 4; ++m)
                #pragma unroll
                for (int n = 0; n < 4; ++n)
                    acc[m][n] = __builtin_amdgcn_mfma_f32_16x16x32_bf16(a4[m], b4[n], acc[m][n], 0, 0, 0);
            FENCE(); __builtin_amdgcn_s_barrier(); FENCE();
            buf = (buf == 2) ? 0 : buf + 1;
        }
    }

    if (sym) {
        // ---- direct store (f16) ----
        #pragma unroll
        for (int m = 0; m < 4; ++m) {
            #pragma unroll
            for (int r = 0; r < 4; ++r) {
                int row = bm + wr * 64 + m * 16 + fg * 4 + r;
                float ra = rA[row];
                #pragma unroll
                for (int n = 0; n < 4; ++n) {
                    int col = bn + wc * 64 + n * 16 + fr;
                    Ch[(long)row * Nn + col] = f2h(acc[m][n][r] * ra * rB[col]);
                }
            }
        }
        if (bn > bm) {
            // ---- mirror store via LDS transpose (f16 out) ----
            float* tbuf = (float*)smb;
            #pragma unroll
            for (int h = 0; h < 2; ++h) {
                __syncthreads();
                if (wc == h) {
                    #pragma unroll
                    for (int m = 0; m < 4; ++m)
                        #pragma unroll
                        for (int r = 0; r < 4; ++r) {
                            int row = wr * 64 + m * 16 + fg * 4 + r;
                            float ra = rA[bm + row];
                            #pragma unroll
                            for (int n = 0; n < 4; ++n) {
                                int cloc = n * 16 + fr;
                                float rb = rB[bn + h * 64 + cloc];
                                tbuf[cloc * 132 + row] = acc[m][n][r] * ra * rb;
                            }
                        }
                }
                __syncthreads();
                #pragma unroll
                for (int q = 0; q < 8; ++q) {
                    int fi = (q * 256 + tid) * 4;    // 0..8191
                    int rp = fi >> 7;                // transposed row 0..63
                    int cp = fi & 127;               // col 0..127 (step 4)
                    ushort4 val = make_ushort4(
                        f2h(tbuf[rp * 132 + cp]),     f2h(tbuf[rp * 132 + cp + 1]),
                        f2h(tbuf[rp * 132 + cp + 2]), f2h(tbuf[rp * 132 + cp + 3]));
                    *(ushort4*)&Ch[(long)(bn + h * 64 + rp) * Nn + bm + cp] = val;
                }
            }
        }
    } else {
        // ---- direct store (f32, projections) ----
        #pragma unroll
        for (int m = 0; m < 4; ++m) {
            #pragma unroll
            for (int r = 0; r < 4; ++r) {
                int row = bm + wr * 64 + m * 16 + fg * 4 + r;
                #pragma unroll
                for (int n = 0; n < 4; ++n) {
                    int col = bn + wc * 64 + n * 16 + fr;
                    Cf[(long)row * Nn + col] = acc[m][n][r];
                }
            }
        }
    }
}

// ---------------- merged top-5 per row + degree counts (packed-key, 4 waves/block) ----------------
__global__ __launch_bounds__(256) void topk_kernel(
    const ushort_t* __restrict__ he_sim, const ushort_t* __restrict__ st_sim,
    const int* __restrict__ mask,
    int* __restrict__ he_idx, int* __restrict__ st_idx,
    int* __restrict__ he_cnt, int* __restrict__ st_cnt)
{
    int gb = blockIdx.x * 4 + (threadIdx.x >> 6);
    int lane = threadIdx.x & 63;
    unsigned k0 = 0, k1 = 0, k2 = 0, k3 = 0, k4 = 0;
    int* outIdx; int* cntp;

    auto skey = [](unsigned h) -> unsigned {
        unsigned s = h >> 15;
        return h ^ (((0u - s) | 0x8000u) & 0xFFFFu);
    };
    auto insk = [&](unsigned key) {
        bool c0 = key > k0, c1 = key > k1, c2 = key > k2, c3 = key > k3, c4 = key > k4;
        k4 = c4 ? (c3 ? k3 : key) : k4;
        k3 = c3 ? (c2 ? k2 : key) : k3;
        k2 = c2 ? (c1 ? k1 : key) : k2;
        k1 = c1 ? (c0 ? k0 : key) : k1;
        k0 = c0 ? key : k0;
    };

    if (gb < NN) {
        int z = gb >> 10;
        const uint4* row8 = (const uint4*)(he_sim + (long)z * PP * PP + (long)(gb & (PP - 1)) * PP);
        outIdx = he_idx + (long)gb * K_HG;
        cntp = he_cnt + z * PP;
        #pragma unroll
        for (int it = 0; it < (PP / 8) / 64; ++it) {      // 2 iters
            int j8 = it * 64 + lane;
            uint4 u = row8[j8];
            unsigned inv = 0xFFFFu - (unsigned)(j8 * 8);
            insk((skey(u.x & 0xFFFFu) << 16) | inv);
            insk((skey(u.x >> 16)     << 16) | (inv - 1));
            insk((skey(u.y & 0xFFFFu) << 16) | (inv - 2));
            insk((skey(u.y >> 16)     << 16) | (inv - 3));
            insk((skey(u.z & 0xFFFFu) << 16) | (inv - 4));
            insk((skey(u.z >> 16)     << 16) | (inv - 5));
            insk((skey(u.w & 0xFFFFu) << 16) | (inv - 6));
            insk((skey(u.w >> 16)     << 16) | (inv - 7));
        }
    } else {
        int g2 = gb - NN;
        int z = g2 >> 11, e = g2 & (MM - 1);
        const int* mk = mask + (long)z * MM;
        outIdx = st_idx + (long)g2 * K_HG;
        cntp = st_cnt + z * MM;
        if (mk[e] == 0) {
            if (lane == 0) {
                #pragma unroll
                for (int r = 0; r < K_HG; ++r) outIdx[r] = -1;
            }
            return;
        }
        const uint4* row8 = (const uint4*)(st_sim + (long)e * MM);
        const int4*  mk4  = (const int4*)mk;
        #pragma unroll
        for (int it = 0; it < (MM / 8) / 64; ++it) {      // 4 iters
            int j8 = it * 64 + lane;
            uint4 u = row8[j8];
            int4 ma = mk4[2 * j8], mb = mk4[2 * j8 + 1];
            unsigned inv = 0xFFFFu - (unsigned)(j8 * 8);
            insk(ma.x ? ((skey(u.x & 0xFFFFu) << 16) | inv)       : 0u);
            insk(ma.y ? ((skey(u.x >> 16)     << 16) | (inv - 1)) : 0u);
            insk(ma.z ? ((skey(u.y & 0xFFFFu) << 16) | (inv - 2)) : 0u);
            insk(ma.w ? ((skey(u.y >> 16)     << 16) | (inv - 3)) : 0u);
            insk(mb.x ? ((skey(u.z & 0xFFFFu) << 16) | (inv - 4)) : 0u);
            insk(mb.y ? ((skey(u.z >> 16)     << 16) | (inv - 5)) : 0u);
            insk(mb.z ? ((skey(u.w & 0xFFFFu) << 16) | (inv - 6)) : 0u);
            insk(mb.w ? ((skey(u.w >> 16)     << 16) | (inv - 7)) : 0u);
        }
    }

    // 5 rounds of wave max merge (keys unique -> exact pop)
    #pragma unroll
    for (int r = 0; r < K_HG; ++r) {
        unsigned bk = k0;
        for (int o = 32; o > 0; o >>= 1) {
            unsigned ok = (unsigned)__shfl_xor((int)bk, o, 64);
            bk = ok > bk ? ok : bk;
        }
        if (lane == 0) {
            int bi = (int)(0xFFFFu - (bk & 0xFFFFu));
            outIdx[r] = bi;
            atomicAdd(&cntp[bi], 1);
        }
        if (k0 == bk) {
            k0 = k1; k1 = k2; k2 = k3; k3 = k4; k4 = 0;
        }
    }
}

// ---------------- merged per-edge value (bf16 out) + capacity-CSR fill ----------------
__global__ __launch_bounds__(256) void edge_kernel(
    const int* __restrict__ he_idx, const int* __restrict__ st_idx,
    const float* __restrict__ Xw_he, const float* __restrict__ Xw_st,
    const int* __restrict__ he_cnt, const int* __restrict__ st_cnt,
    int* __restrict__ he_cur, int* __restrict__ st_cur,
    int* __restrict__ he_inv, int* __restrict__ st_inv,
    ushort_t* __restrict__ he_ev, ushort_t* __restrict__ st_ev)
{
    int b = blockIdx.x;
    const int *idx, *cnt; const float* Xw;
    int *cur, *inv; ushort_t* ev;
    int ge, gbase, rowsPerZ; long xwBase;
    if (b < NN) {
        ge = b; int z = ge >> 10;
        idx = he_idx; Xw = Xw_he; cnt = he_cnt;
        cur = he_cur; inv = he_inv; ev = he_ev;
        rowsPerZ = PP; gbase = z * PP; xwBase = (long)z * PP;
    } else {
        ge = b - NN; int z = ge >> 11;
        idx = st_idx; Xw = Xw_st; cnt = st_cnt;
        cur = st_cur; inv = st_inv; ev = st_ev;
        rowsPerZ = MM; gbase = z * MM; xwBase = 0;
    }
    int mm[K_HG];
    #pragma unroll
    for (int k = 0; k < K_HG; ++k) mm[k] = idx[(long)ge * K_HG + k];
    if (mm[0] < 0) return;   // masked-out ST edge
    int d = threadIdx.x;
    float val = 0.0f;
    #pragma unroll
    for (int k = 0; k < K_HG; ++k) {
        int m = mm[k];
        if (m < 0 || m >= rowsPerZ) continue;
        float w = rsqrtf(fmaxf((float)cnt[gbase + m], EPSF));
        val += w * Xw[(xwBase + m) * D_OUT + d];
    }
    ev[(long)ge * D_OUT + d] = f2bf(val * (1.0f / (float)K_HG));
    if (d < K_HG) {
        int m = mm[d];
        if (m >= 0 && m < rowsPerZ) {
            int g = gbase + m;
            int pos = atomicAdd(&cur[g], 1);
            if (pos < DEG_CAP) inv[(long)g * DEG_CAP + pos] = ge;
        }
    }
}

// ---------------- node gather + Dv^-1/2 + GELU + atomic pool into z ----------------
__global__ __launch_bounds__(256) void pool_gather_kernel(
    const ushort_t* __restrict__ he_ev, const ushort_t* __restrict__ st_ev,
    const int* __restrict__ he_cnt, const int* __restrict__ st_cnt,
    const int* __restrict__ he_inv, const int* __restrict__ st_inv,
    const int* __restrict__ mask,
    float* __restrict__ zacc_he, float* __restrict__ zacc_st)
{
    int blk = blockIdx.x;
    const ushort_t* ev; const int *cnt, *inv, *msk = nullptr;
    float* zt; int gbase, i0;
    if (blk < VV * HE_NCH) {
        int z = blk / HE_NCH, c = blk % HE_NCH;
        ev = he_ev; cnt = he_cnt; inv = he_inv;
        zt = zacc_he + z * D_OUT;
        gbase = z * PP; i0 = c * POOL_CHUNK;
    } else {
        int b2 = blk - VV * HE_NCH;
        int z = b2 / ST_NCH, c = b2 % ST_NCH;
        ev = st_ev; cnt = st_cnt; inv = st_inv;
        msk = mask;
        zt = zacc_st + z * D_OUT;
        gbase = z * MM; i0 = c * POOL_CHUNK;
    }
    int d = threadIdx.x;
    float s = 0.0f;
    bool any = false;
    #pragma unroll
    for (int i = 0; i < POOL_CHUNK; ++i) {
        int g = gbase + i0 + i;
        if (msk && msk[g] == 0) continue;
        any = true;
        int cn = cnt[g];
        const int* ip = inv + (long)g * DEG_CAP;
        float a = 0.0f;
        for (int e = 0; e < cn; ++e)
            a += bf2f(ev[(long)ip[e] * D_OUT + d]);
        float w = rsqrtf(fmaxf((float)cn, EPSF));
        float x = w * a;
        s += 0.5f * x * (1.0f + erff(x * 0.70710678118654752f));   // exact GELU
    }
    if (any || !msk) atomicAdd(&zt[d], s);
}

// ---------------- final: divide + l2norm + contrastive loss ----------------
__global__ __launch_bounds__(64) void final_kernel(const float* __restrict__ zacc_he,
                                                   const float* __restrict__ zacc_st,
                                                   const int* __restrict__ maskcnt,
                                                   float* __restrict__ out) {
    __shared__ float he[VV][D_OUT];
    __shared__ float st[VV][D_OUT];
    __shared__ float lg[VV][VV];
    __shared__ float rn_he[VV], rn_st[VV];
    int t = threadIdx.x;
    for (int i = t; i < VV * D_OUT; i += 64) {
        int v = i >> 8;
        he[v][i & 255] = zacc_he[i] / (float)PP;
        st[v][i & 255] = zacc_st[i] / (float)maskcnt[v];
    }
    __syncthreads();
    if (t < VV) {
        float s = 0.0f;
        for (int d2 = 0; d2 < D_OUT; ++d2) s += he[t][d2] * he[t][d2];
        rn_he[t] = 1.0f / fmaxf(sqrtf(s), EPSF);
    } else if (t < 2 * VV) {
        int v = t - VV; float s = 0.0f;
        for (int d2 = 0; d2 < D_OUT; ++d2) s += st[v][d2] * st[v][d2];
        rn_st[v] = 1.0f / fmaxf(sqrtf(s), EPSF);
    }
    __syncthreads();
    int v = t >> 3, w2 = t & 7;
    float dot = 0.0f;
    for (int d2 = 0; d2 < D_OUT; ++d2) dot += he[v][d2] * st[w2][d2];
    lg[v][w2] = dot * rn_he[v] * rn_st[w2] / TEMP;
    __syncthreads();
    if (t == 0) {
        float l1 = 0.0f, l2 = 0.0f;
        for (int i = 0; i < VV; ++i) {
            float mx = -1e30f;
            for (int jj = 0; jj < VV; ++jj) mx = fmaxf(mx, lg[i][jj]);
            float se = 0.0f;
            for (int jj = 0; jj < VV; ++jj) se += expf(lg[i][jj] - mx);
            l1 += lg[i][i] - (mx + logf(se));
            float mx2 = -1e30f;
            for (int jj = 0; jj < VV; ++jj) mx2 = fmaxf(mx2, lg[jj][i]);
            float se2 = 0.0f;
            for (int jj = 0; jj < VV; ++jj) se2 += expf(lg[jj][i] - mx2);
            l2 += lg[i][i] - (mx2 + logf(se2));
        }
        out[0] = 0.5f * (-(l1 / (float)VV) - (l2 / (float)VV));
    }
}

// ---------------- launch ----------------
extern "C" void kernel_launch(void* const* d_in, const int* in_sizes, int n_in,
                              void* d_out, int out_size, void* d_ws, size_t ws_size,
                              hipStream_t stream) {
    const float* F    = (const float*)d_in[0];
    const float* T    = (const float*)d_in[1];
    const float* E    = (const float*)d_in[3];
    const float* S    = (const float*)d_in[4];
    const float* W_he = (const float*)d_in[5];
    const float* W_st = (const float*)d_in[6];
    float* out = (float*)d_out;

    size_t off = 0;
    auto take = [&](size_t bytes) -> void* {
        void* p = (char*)d_ws + off;
        off += (bytes + 255) & ~(size_t)255;
        return p;
    };
    ushort_t* Fs    = (ushort_t*)take((size_t)NN * 2 * HE_DIM * 2);   // 33.5 MB
    ushort_t* Es    = (ushort_t*)take((size_t)MM * 2 * ST_DIM * 2);   // 4.2 MB
    ushort_t* Whes  = (ushort_t*)take((size_t)D_OUT * 2 * HE_DIM * 2);
    ushort_t* Wsts  = (ushort_t*)take((size_t)D_OUT * 2 * ST_DIM * 2);
    float* Xw_he    = (float*)take((size_t)NN * D_OUT * 4);           // 8 MB
    float* Xw_st    = (float*)take((size_t)MM * D_OUT * 4);           // 2 MB
    float* rnF      = (float*)take((size_t)NN * 4);
    float* rnE      = (float*)take((size_t)MM * 4);
    int*   mask     = (int*)  take((size_t)VV * MM * 4);
    int*   maskcnt  = (int*)  take((size_t)VV * 4);
    ushort_t* he_sim = (ushort_t*)take((size_t)VV * PP * PP * 2);     // 16 MB (f16)
    ushort_t* st_sim = (ushort_t*)take((size_t)MM * MM * 2);          // 8 MB (f16)
    int*   he_idx   = (int*)  take((size_t)NN * K_HG * 4);
    int*   st_idx   = (int*)  take((size_t)VV * MM * K_HG * 4);
    // zero-init region (zeroed inside prep): counts + cursors + z accumulators
    size_t zero_beg = off;
    int*   he_cnt   = (int*)  take((size_t)NN * 4);
    int*   st_cnt   = (int*)  take((size_t)VV * MM * 4);
    int*   he_cur   = (int*)  take((size_t)NN * 4);
    int*   st_cur   = (int*)  take((size_t)VV * MM * 4);
    float* zacc_he  = (float*)take((size_t)VV * D_OUT * 4);
    float* zacc_st  = (float*)take((size_t)VV * D_OUT * 4);
    size_t zero_end = off;
    int*   he_inv   = (int*)  take((size_t)NN * DEG_CAP * 4);         // 3 MB
    int*   st_inv   = (int*)  take((size_t)VV * MM * DEG_CAP * 4);    // 6 MB
    ushort_t* he_ev = (ushort_t*)take((size_t)NN * D_OUT * 2);        // 4 MB (bf16)
    ushort_t* st_ev = (ushort_t*)take((size_t)VV * MM * D_OUT * 2);   // 8 MB (bf16)

    int nZeroInts = (int)((zero_end - zero_beg) / 4);

    // split hi/lo + row norms + centroids/mask + zeroing (one launch)
    prep_kernel<<<NPREP + VV, 256, 0, stream>>>(F, E, W_he, W_st, T, S,
                                                Fs, Es, Whes, Wsts, rnF, rnE,
                                                mask, maskcnt,
                                                (int*)((char*)d_ws + zero_beg), nZeroInts);

    // all four GEMMs in one grouped launch (HE 1 / ST 1 / proj 2 passes)
    gemm_grouped<<<NB_ALL, 256, 0, stream>>>(Fs, Es, Whes, Wsts,
                                             he_sim, st_sim, Xw_he, Xw_st,
                                             rnF, rnE);

    // top-5 + degree counts (packed integer keys, 4 waves/block)
    topk_kernel<<<(NN + VV * MM) / 4, 256, 0, stream>>>(he_sim, st_sim, mask,
                                                        he_idx, st_idx, he_cnt, st_cnt);
    // per-edge values (bf16) + capacity-based inverse fill
    edge_kernel<<<NN + VV * MM, 256, 0, stream>>>(he_idx, st_idx, Xw_he, Xw_st,
                                                  he_cnt, st_cnt,
                                                  he_cur, st_cur, he_inv, st_inv,
                                                  he_ev, st_ev);
    // gather + gelu + atomic pool directly into z accumulators
    pool_gather_kernel<<<VV * HE_NCH + VV * ST_NCH, 256, 0, stream>>>(
        he_ev, st_ev, he_cnt, st_cnt, he_inv, st_inv,
        mask, zacc_he, zacc_st);
    // divide + loss
    final_kernel<<<1, 64, 0, stream>>>(zacc_he, zacc_st, maskcnt, out);
}

// Round 23
// 126.646 us; speedup vs baseline: 1.2936x; 1.0324x over previous
//
#include <hip/hip_runtime.h>
#include <hip/hip_bf16.h>
#include <hip/hip_fp16.h>
#include <math.h>

// ---------------- problem constants ----------------
#define NN      8192
#define VV      8
#define PP      1024      // N / V
#define MM      2048
#define HE_DIM  1024
#define ST_DIM  512
#define D_OUT   256
#define K_HG    5
#define RADIUS  150.0f
#define TEMP    0.07f
#define EPSF    1e-12f

#define POOL_CHUNK 4
#define HE_NCH  (PP / POOL_CHUNK)   // 256
#define ST_NCH  (MM / POOL_CHUNK)   // 512
#define DEG_CAP 96                  // max node in-degree (KNN in-degree max ~20)

// grouped-GEMM block ranges
#define HE_TRI   36                 // 8x8 upper triangle
#define ST_TRI   136                // 16x16 upper triangle
#define NB_HE    (VV * HE_TRI)      // 288
#define NB_ST    ST_TRI             // 136
#define NB_PH    ((NN / 128) * (D_OUT / 128))   // 128
#define NB_PS    ((MM / 128) * (D_OUT / 128))   // 32
#define NB_ALL   (NB_HE + NB_ST + NB_PH + NB_PS) // 584 = 8 * 73

#define NPREP   (NN + MM + 2 * D_OUT)   // rows handled by prep; +VV extra blocks

typedef __bf16 bf16x8 __attribute__((ext_vector_type(8)));
typedef float  f32x4  __attribute__((ext_vector_type(4)));
typedef unsigned short ushort_t;

typedef __attribute__((address_space(1))) void gvoid;
typedef __attribute__((address_space(3))) void svoid;
#define GLOAD16(g, l) __builtin_amdgcn_global_load_lds((gvoid*)(g), (svoid*)(l), 16, 0, 0)
#define FENCE() asm volatile("" ::: "memory")

__device__ __forceinline__ ushort_t f2bf(float x) {
    unsigned int b = __float_as_uint(x);
    return (ushort_t)((b + 0x7fffu + ((b >> 16) & 1u)) >> 16);   // RNE
}
__device__ __forceinline__ float bf2f(ushort_t h) {
    return __uint_as_float(((unsigned int)h) << 16);
}
__device__ __forceinline__ ushort_t f2h(float x) {
    return __half_as_ushort(__float2half_rn(x));
}

// ---------------- fused: bf16 cast + rownorm + (centers/mask/zero in tail blocks) ----------------
__global__ __launch_bounds__(256) void prep_kernel(
    const float* __restrict__ F, const float* __restrict__ E,
    const float* __restrict__ Whe, const float* __restrict__ Wst,
    const float* __restrict__ T, const float* __restrict__ S,
    ushort_t* __restrict__ Fs, ushort_t* __restrict__ Es,
    ushort_t* __restrict__ Whes, ushort_t* __restrict__ Wsts,
    float* __restrict__ rnF, float* __restrict__ rnE,
    int* __restrict__ mask, int* __restrict__ maskcnt,
    int* __restrict__ zeroPtr, int nZeroInts)
{
    int b = blockIdx.x;
    if (b >= NPREP) {
        int v = b - NPREP;
        int per = (nZeroInts + VV - 1) / VV;
        for (int i = threadIdx.x; i < per; i += 256) {
            int idx = v * per + i;
            if (idx < nZeroInts) zeroPtr[idx] = 0;
        }
        float sx = 0.0f, sy = 0.0f;
        for (int i = threadIdx.x; i < PP; i += 256) {
            sx += T[(long)(v * PP + i) * 2 + 0];
            sy += T[(long)(v * PP + i) * 2 + 1];
        }
        __shared__ float rx[256], ry[256];
        __shared__ int   rc[256];
        rx[threadIdx.x] = sx; ry[threadIdx.x] = sy; __syncthreads();
        for (int o = 128; o > 0; o >>= 1) {
            if (threadIdx.x < o) { rx[threadIdx.x] += rx[threadIdx.x + o]; ry[threadIdx.x] += ry[threadIdx.x + o]; }
            __syncthreads();
        }
        float cx = rx[0] / (float)PP, cy = ry[0] / (float)PP;
        __syncthreads();
        int cnt = 0;
        for (int m = threadIdx.x; m < MM; m += 256) {
            float dx = cx - S[m * 2 + 0];
            float dy = cy - S[m * 2 + 1];
            int in = (sqrtf(dx * dx + dy * dy) < RADIUS) ? 1 : 0;
            mask[v * MM + m] = in;
            cnt += in;
        }
        rc[threadIdx.x] = cnt; __syncthreads();
        for (int o = 128; o > 0; o >>= 1) {
            if (threadIdx.x < o) rc[threadIdx.x] += rc[threadIdx.x + o];
            __syncthreads();
        }
        if (threadIdx.x == 0) maskcnt[v] = rc[0];
        return;
    }
    const float* src; ushort_t* dst; float* rn; int K; long row;
    if (b < NN)                    { src = F;   dst = Fs;   rn = rnF;    K = HE_DIM; row = b; }
    else if (b < NN + MM)          { src = E;   dst = Es;   rn = rnE;    K = ST_DIM; row = b - NN; }
    else if (b < NN + MM + D_OUT)  { src = Whe; dst = Whes; rn = nullptr; K = HE_DIM; row = b - NN - MM; }
    else                           { src = Wst; dst = Wsts; rn = nullptr; K = ST_DIM; row = b - NN - MM - D_OUT; }
    const float4* srow = (const float4*)(src + row * (long)K);
    ushort_t* drow = dst + row * (long)K;
    float s = 0.0f;
    for (int j4 = threadIdx.x; j4 < (K >> 2); j4 += 256) {
        float4 x = srow[j4];
        float xs[4] = {x.x, x.y, x.z, x.w};
        ushort_t hs[4];
        #pragma unroll
        for (int t = 0; t < 4; ++t) {
            hs[t] = f2bf(xs[t]);
            s += xs[t] * xs[t];
        }
        *(ushort4*)(drow + j4 * 4) = make_ushort4(hs[0], hs[1], hs[2], hs[3]);
    }
    if (rn) {
        __shared__ float red[256];
        red[threadIdx.x] = s; __syncthreads();
        for (int o = 128; o > 0; o >>= 1) {
            if (threadIdx.x < o) red[threadIdx.x] += red[threadIdx.x + o];
            __syncthreads();
        }
        if (threadIdx.x == 0) rn[row] = 1.0f / fmaxf(sqrtf(red[0]), EPSF);
    }
}

// ---------------- grouped bf16 MFMA GEMM ----------------
// Single pass, 3-buf {A,B} 16 KB bufs, depth-2 prefetch, counted vmcnt.
// 48 KB LDS -> 3 blocks/CU. Buffers are [rows][K] bf16 (contiguous).
__global__ __launch_bounds__(256) void gemm_grouped(
    const ushort_t* __restrict__ Fs, const ushort_t* __restrict__ Es,
    const ushort_t* __restrict__ Whes, const ushort_t* __restrict__ Wsts,
    ushort_t* __restrict__ he_sim, ushort_t* __restrict__ st_sim,
    float* __restrict__ Xw_he, float* __restrict__ Xw_st,
    const float* __restrict__ rnF, const float* __restrict__ rnE)
{
    // XCD map: per-xcd order = proj (longest with HE), ST, then HE (own-region tiles).
    int bid = blockIdx.x;
    int xcd = bid & 7, j = bid >> 3;    // j in [0,73); 584 = 8*73 bijective
    int id;
    if (j < 20)      id = NB_HE + (17 + j) * 8 + xcd;    // proj: rest-rows 17..36
    else if (j < 37) id = NB_HE + (j - 20) * 8 + xcd;    // ST:   rest-rows 0..16
    else             id = xcd * HE_TRI + (j - 37);       // HE:   own region

    const ushort_t *A, *B; ushort_t *Ch = nullptr; float *Cf = nullptr;
    const float *rA = nullptr, *rB = nullptr;
    int K, Nn, bm, bn, sym;
    if (id < NB_HE) {
        int z = id / HE_TRI, t = id - z * HE_TRI;
        int i = 0;
        while (t >= 8 - i) { t -= 8 - i; ++i; }
        bm = i * 128; bn = (i + t) * 128;
        A = B = Fs + (long)z * PP * HE_DIM;
        Ch = he_sim + (long)z * PP * PP;
        rA = rB = rnF + z * PP;
        K = HE_DIM; Nn = PP; sym = 1;
    } else if (id < NB_HE + NB_ST) {
        int t = id - NB_HE;
        int i = 0;
        while (t >= 16 - i) { t -= 16 - i; ++i; }
        bm = i * 128; bn = (i + t) * 128;
        A = B = Es; Ch = st_sim; rA = rB = rnE;
        K = ST_DIM; Nn = MM; sym = 1;
    } else if (id < NB_HE + NB_ST + NB_PH) {
        int t = id - (NB_HE + NB_ST);
        bm = (t >> 1) * 128; bn = (t & 1) * 128;
        A = Fs; B = Whes; Cf = Xw_he;
        K = HE_DIM; Nn = D_OUT; sym = 0;
    } else {
        int t = id - (NB_HE + NB_ST + NB_PH);
        bm = (t >> 1) * 128; bn = (t & 1) * 128;
        A = Es; B = Wsts; Cf = Xw_st;
        K = ST_DIM; Nn = D_OUT; sym = 0;
    }

    __shared__ ushort_t sm[24576];   // 48 KB: 3 bufs x {A 8KB, B 8KB}
    char* const smb = (char*)&sm[0];
    const int tid  = threadIdx.x;
    const int lane = tid & 63, wave = tid >> 6;
    const int wr = wave >> 1, wc = wave & 1;
    const int fr = lane & 15, fg = lane >> 4;

    const long lda = (long)K;
    const int srow = wave * 16 + (lane >> 2);
    const int scol = (((lane & 3) ^ ((srow >> 1) & 3)) * 8);  // pre-swizzled src col

    f32x4 acc[4][4] = {};

    auto roA = [&](int m) { int row = wr * 64 + m * 16 + fr;
                            return row * 64 + ((fg ^ ((row >> 1) & 3)) * 16); };
    auto roB = [&](int n) { int row = wc * 64 + n * 16 + fr;
                            return row * 64 + ((fg ^ ((row >> 1) & 3)) * 16); };

    auto STG = [&](int kk, int b) {
        const ushort_t* ga = A + (long)(bm + srow) * lda + kk + scol;
        const ushort_t* gb = B + (long)(bn + srow) * lda + kk + scol;
        char* AT = smb + b * 16384 + wave * 1024;
        char* BT = AT + 8192;
        GLOAD16(ga, AT); GLOAD16(ga + 64 * lda, AT + 4096);
        GLOAD16(gb, BT); GLOAD16(gb + 64 * lda, BT + 4096);
    };
    STG(0, 0); STG(32, 1);
    int buf = 0;
    for (int kk = 0; kk < K; kk += 32) {
        if (kk + 64 < K) {
            STG(kk + 64, buf == 0 ? 2 : buf - 1);
            asm volatile("s_waitcnt vmcnt(8)" ::: "memory");
        } else if (kk + 32 < K) {
            asm volatile("s_waitcnt vmcnt(4)" ::: "memory");
        } else {
            asm volatile("s_waitcnt vmcnt(0)" ::: "memory");
        }
        FENCE(); __builtin_amdgcn_s_barrier(); FENCE();
        const char* ab = smb + buf * 16384;
        bf16x8 a4[4], b4[4];
        #pragma unroll
        for (int m = 0; m < 4; ++m) a4[m] = *(const bf16x8*)(ab + roA(m));
        #pragma unroll
        for (int n = 0; n < 4; ++n) b4[n] = *(const bf16x8*)(ab + 8192 + roB(n));
        #pragma unroll
        for (int m = 0; m < 4; ++m)
            #pragma unroll
            for (int n = 0; n < 4; ++n)
                acc[m][n] = __builtin_amdgcn_mfma_f32_16x16x32_bf16(a4[m], b4[n], acc[m][n], 0, 0, 0);
        FENCE(); __builtin_amdgcn_s_barrier(); FENCE();
        buf = (buf == 2) ? 0 : buf + 1;
    }

    if (sym) {
        // ---- direct store (f16) ----
        #pragma unroll
        for (int m = 0; m < 4; ++m) {
            #pragma unroll
            for (int r = 0; r < 4; ++r) {
                int row = bm + wr * 64 + m * 16 + fg * 4 + r;
                float ra = rA[row];
                #pragma unroll
                for (int n = 0; n < 4; ++n) {
                    int col = bn + wc * 64 + n * 16 + fr;
                    Ch[(long)row * Nn + col] = f2h(acc[m][n][r] * ra * rB[col]);
                }
            }
        }
        if (bn > bm) {
            // ---- mirror store via LDS transpose (f16 out) ----
            float* tbuf = (float*)smb;
            #pragma unroll
            for (int h = 0; h < 2; ++h) {
                __syncthreads();
                if (wc == h) {
                    #pragma unroll
                    for (int m = 0; m < 4; ++m)
                        #pragma unroll
                        for (int r = 0; r < 4; ++r) {
                            int row = wr * 64 + m * 16 + fg * 4 + r;
                            float ra = rA[bm + row];
                            #pragma unroll
                            for (int n = 0; n < 4; ++n) {
                                int cloc = n * 16 + fr;
                                float rb = rB[bn + h * 64 + cloc];
                                tbuf[cloc * 132 + row] = acc[m][n][r] * ra * rb;
                            }
                        }
                }
                __syncthreads();
                #pragma unroll
                for (int q = 0; q < 8; ++q) {
                    int fi = (q * 256 + tid) * 4;    // 0..8191
                    int rp = fi >> 7;                // transposed row 0..63
                    int cp = fi & 127;               // col 0..127 (step 4)
                    ushort4 val = make_ushort4(
                        f2h(tbuf[rp * 132 + cp]),     f2h(tbuf[rp * 132 + cp + 1]),
                        f2h(tbuf[rp * 132 + cp + 2]), f2h(tbuf[rp * 132 + cp + 3]));
                    *(ushort4*)&Ch[(long)(bn + h * 64 + rp) * Nn + bm + cp] = val;
                }
            }
        }
    } else {
        // ---- direct store (f32, projections) ----
        #pragma unroll
        for (int m = 0; m < 4; ++m) {
            #pragma unroll
            for (int r = 0; r < 4; ++r) {
                int row = bm + wr * 64 + m * 16 + fg * 4 + r;
                #pragma unroll
                for (int n = 0; n < 4; ++n) {
                    int col = bn + wc * 64 + n * 16 + fr;
                    Cf[(long)row * Nn + col] = acc[m][n][r];
                }
            }
        }
    }
}

// ---------------- merged top-5 per row + degree counts (packed-key, 4 waves/block) ----------------
__global__ __launch_bounds__(256) void topk_kernel(
    const ushort_t* __restrict__ he_sim, const ushort_t* __restrict__ st_sim,
    const int* __restrict__ mask,
    int* __restrict__ he_idx, int* __restrict__ st_idx,
    int* __restrict__ he_cnt, int* __restrict__ st_cnt)
{
    int gb = blockIdx.x * 4 + (threadIdx.x >> 6);
    int lane = threadIdx.x & 63;
    unsigned k0 = 0, k1 = 0, k2 = 0, k3 = 0, k4 = 0;
    int* outIdx; int* cntp;

    auto skey = [](unsigned h) -> unsigned {
        unsigned s = h >> 15;
        return h ^ (((0u - s) | 0x8000u) & 0xFFFFu);
    };
    auto insk = [&](unsigned key) {
        bool c0 = key > k0, c1 = key > k1, c2 = key > k2, c3 = key > k3, c4 = key > k4;
        k4 = c4 ? (c3 ? k3 : key) : k4;
        k3 = c3 ? (c2 ? k2 : key) : k3;
        k2 = c2 ? (c1 ? k1 : key) : k2;
        k1 = c1 ? (c0 ? k0 : key) : k1;
        k0 = c0 ? key : k0;
    };

    if (gb < NN) {
        int z = gb >> 10;
        const uint4* row8 = (const uint4*)(he_sim + (long)z * PP * PP + (long)(gb & (PP - 1)) * PP);
        outIdx = he_idx + (long)gb * K_HG;
        cntp = he_cnt + z * PP;
        #pragma unroll
        for (int it = 0; it < (PP / 8) / 64; ++it) {      // 2 iters
            int j8 = it * 64 + lane;
            uint4 u = row8[j8];
            unsigned inv = 0xFFFFu - (unsigned)(j8 * 8);
            insk((skey(u.x & 0xFFFFu) << 16) | inv);
            insk((skey(u.x >> 16)     << 16) | (inv - 1));
            insk((skey(u.y & 0xFFFFu) << 16) | (inv - 2));
            insk((skey(u.y >> 16)     << 16) | (inv - 3));
            insk((skey(u.z & 0xFFFFu) << 16) | (inv - 4));
            insk((skey(u.z >> 16)     << 16) | (inv - 5));
            insk((skey(u.w & 0xFFFFu) << 16) | (inv - 6));
            insk((skey(u.w >> 16)     << 16) | (inv - 7));
        }
    } else {
        int g2 = gb - NN;
        int z = g2 >> 11, e = g2 & (MM - 1);
        const int* mk = mask + (long)z * MM;
        outIdx = st_idx + (long)g2 * K_HG;
        cntp = st_cnt + z * MM;
        if (mk[e] == 0) {
            if (lane == 0) {
                #pragma unroll
                for (int r = 0; r < K_HG; ++r) outIdx[r] = -1;
            }
            return;
        }
        const uint4* row8 = (const uint4*)(st_sim + (long)e * MM);
        const int4*  mk4  = (const int4*)mk;
        #pragma unroll
        for (int it = 0; it < (MM / 8) / 64; ++it) {      // 4 iters
            int j8 = it * 64 + lane;
            uint4 u = row8[j8];
            int4 ma = mk4[2 * j8], mb = mk4[2 * j8 + 1];
            unsigned inv = 0xFFFFu - (unsigned)(j8 * 8);
            insk(ma.x ? ((skey(u.x & 0xFFFFu) << 16) | inv)       : 0u);
            insk(ma.y ? ((skey(u.x >> 16)     << 16) | (inv - 1)) : 0u);
            insk(ma.z ? ((skey(u.y & 0xFFFFu) << 16) | (inv - 2)) : 0u);
            insk(ma.w ? ((skey(u.y >> 16)     << 16) | (inv - 3)) : 0u);
            insk(mb.x ? ((skey(u.z & 0xFFFFu) << 16) | (inv - 4)) : 0u);
            insk(mb.y ? ((skey(u.z >> 16)     << 16) | (inv - 5)) : 0u);
            insk(mb.z ? ((skey(u.w & 0xFFFFu) << 16) | (inv - 6)) : 0u);
            insk(mb.w ? ((skey(u.w >> 16)     << 16) | (inv - 7)) : 0u);
        }
    }

    // 5 rounds of wave max merge (keys unique -> exact pop)
    #pragma unroll
    for (int r = 0; r < K_HG; ++r) {
        unsigned bk = k0;
        for (int o = 32; o > 0; o >>= 1) {
            unsigned ok = (unsigned)__shfl_xor((int)bk, o, 64);
            bk = ok > bk ? ok : bk;
        }
        if (lane == 0) {
            int bi = (int)(0xFFFFu - (bk & 0xFFFFu));
            outIdx[r] = bi;
            atomicAdd(&cntp[bi], 1);
        }
        if (k0 == bk) {
            k0 = k1; k1 = k2; k2 = k3; k3 = k4; k4 = 0;
        }
    }
}

// ---------------- merged per-edge value (bf16 out) + capacity-CSR fill ----------------
__global__ __launch_bounds__(256) void edge_kernel(
    const int* __restrict__ he_idx, const int* __restrict__ st_idx,
    const float* __restrict__ Xw_he, const float* __restrict__ Xw_st,
    const int* __restrict__ he_cnt, const int* __restrict__ st_cnt,
    int* __restrict__ he_cur, int* __restrict__ st_cur,
    int* __restrict__ he_inv, int* __restrict__ st_inv,
    ushort_t* __restrict__ he_ev, ushort_t* __restrict__ st_ev)
{
    int b = blockIdx.x;
    const int *idx, *cnt; const float* Xw;
    int *cur, *inv; ushort_t* ev;
    int ge, gbase, rowsPerZ; long xwBase;
    if (b < NN) {
        ge = b; int z = ge >> 10;
        idx = he_idx; Xw = Xw_he; cnt = he_cnt;
        cur = he_cur; inv = he_inv; ev = he_ev;
        rowsPerZ = PP; gbase = z * PP; xwBase = (long)z * PP;
    } else {
        ge = b - NN; int z = ge >> 11;
        idx = st_idx; Xw = Xw_st; cnt = st_cnt;
        cur = st_cur; inv = st_inv; ev = st_ev;
        rowsPerZ = MM; gbase = z * MM; xwBase = 0;
    }
    int mm[K_HG];
    #pragma unroll
    for (int k = 0; k < K_HG; ++k) mm[k] = idx[(long)ge * K_HG + k];
    if (mm[0] < 0) return;   // masked-out ST edge
    int d = threadIdx.x;
    float val = 0.0f;
    #pragma unroll
    for (int k = 0; k < K_HG; ++k) {
        int m = mm[k];
        if (m < 0 || m >= rowsPerZ) continue;
        float w = rsqrtf(fmaxf((float)cnt[gbase + m], EPSF));
        val += w * Xw[(xwBase + m) * D_OUT + d];
    }
    ev[(long)ge * D_OUT + d] = f2bf(val * (1.0f / (float)K_HG));
    if (d < K_HG) {
        int m = mm[d];
        if (m >= 0 && m < rowsPerZ) {
            int g = gbase + m;
            int pos = atomicAdd(&cur[g], 1);
            if (pos < DEG_CAP) inv[(long)g * DEG_CAP + pos] = ge;
        }
    }
}

// ---------------- node gather + Dv^-1/2 + GELU + atomic pool into z ----------------
__global__ __launch_bounds__(256) void pool_gather_kernel(
    const ushort_t* __restrict__ he_ev, const ushort_t* __restrict__ st_ev,
    const int* __restrict__ he_cnt, const int* __restrict__ st_cnt,
    const int* __restrict__ he_inv, const int* __restrict__ st_inv,
    const int* __restrict__ mask,
    float* __restrict__ zacc_he, float* __restrict__ zacc_st)
{
    int blk = blockIdx.x;
    const ushort_t* ev; const int *cnt, *inv, *msk = nullptr;
    float* zt; int gbase, i0;
    if (blk < VV * HE_NCH) {
        int z = blk / HE_NCH, c = blk % HE_NCH;
        ev = he_ev; cnt = he_cnt; inv = he_inv;
        zt = zacc_he + z * D_OUT;
        gbase = z * PP; i0 = c * POOL_CHUNK;
    } else {
        int b2 = blk - VV * HE_NCH;
        int z = b2 / ST_NCH, c = b2 % ST_NCH;
        ev = st_ev; cnt = st_cnt; inv = st_inv;
        msk = mask;
        zt = zacc_st + z * D_OUT;
        gbase = z * MM; i0 = c * POOL_CHUNK;
    }
    int d = threadIdx.x;
    float s = 0.0f;
    bool any = false;
    #pragma unroll
    for (int i = 0; i < POOL_CHUNK; ++i) {
        int g = gbase + i0 + i;
        if (msk && msk[g] == 0) continue;
        any = true;
        int cn = cnt[g];
        const int* ip = inv + (long)g * DEG_CAP;
        float a = 0.0f;
        for (int e = 0; e < cn; ++e)
            a += bf2f(ev[(long)ip[e] * D_OUT + d]);
        float w = rsqrtf(fmaxf((float)cn, EPSF));
        float x = w * a;
        s += 0.5f * x * (1.0f + erff(x * 0.70710678118654752f));   // exact GELU
    }
    if (any || !msk) atomicAdd(&zt[d], s);
}

// ---------------- final: divide + l2norm + contrastive loss ----------------
__global__ __launch_bounds__(64) void final_kernel(const float* __restrict__ zacc_he,
                                                   const float* __restrict__ zacc_st,
                                                   const int* __restrict__ maskcnt,
                                                   float* __restrict__ out) {
    __shared__ float he[VV][D_OUT];
    __shared__ float st[VV][D_OUT];
    __shared__ float lg[VV][VV];
    __shared__ float rn_he[VV], rn_st[VV];
    int t = threadIdx.x;
    for (int i = t; i < VV * D_OUT; i += 64) {
        int v = i >> 8;
        he[v][i & 255] = zacc_he[i] / (float)PP;
        st[v][i & 255] = zacc_st[i] / (float)maskcnt[v];
    }
    __syncthreads();
    if (t < VV) {
        float s = 0.0f;
        for (int d2 = 0; d2 < D_OUT; ++d2) s += he[t][d2] * he[t][d2];
        rn_he[t] = 1.0f / fmaxf(sqrtf(s), EPSF);
    } else if (t < 2 * VV) {
        int v = t - VV; float s = 0.0f;
        for (int d2 = 0; d2 < D_OUT; ++d2) s += st[v][d2] * st[v][d2];
        rn_st[v] = 1.0f / fmaxf(sqrtf(s), EPSF);
    }
    __syncthreads();
    int v = t >> 3, w2 = t & 7;
    float dot = 0.0f;
    for (int d2 = 0; d2 < D_OUT; ++d2) dot += he[v][d2] * st[w2][d2];
    lg[v][w2] = dot * rn_he[v] * rn_st[w2] / TEMP;
    __syncthreads();
    if (t == 0) {
        float l1 = 0.0f, l2 = 0.0f;
        for (int i = 0; i < VV; ++i) {
            float mx = -1e30f;
            for (int jj = 0; jj < VV; ++jj) mx = fmaxf(mx, lg[i][jj]);
            float se = 0.0f;
            for (int jj = 0; jj < VV; ++jj) se += expf(lg[i][jj] - mx);
            l1 += lg[i][i] - (mx + logf(se));
            float mx2 = -1e30f;
            for (int jj = 0; jj < VV; ++jj) mx2 = fmaxf(mx2, lg[jj][i]);
            float se2 = 0.0f;
            for (int jj = 0; jj < VV; ++jj) se2 += expf(lg[jj][i] - mx2);
            l2 += lg[i][i] - (mx2 + logf(se2));
        }
        out[0] = 0.5f * (-(l1 / (float)VV) - (l2 / (float)VV));
    }
}

// ---------------- launch ----------------
extern "C" void kernel_launch(void* const* d_in, const int* in_sizes, int n_in,
                              void* d_out, int out_size, void* d_ws, size_t ws_size,
                              hipStream_t stream) {
    const float* F    = (const float*)d_in[0];
    const float* T    = (const float*)d_in[1];
    const float* E    = (const float*)d_in[3];
    const float* S    = (const float*)d_in[4];
    const float* W_he = (const float*)d_in[5];
    const float* W_st = (const float*)d_in[6];
    float* out = (float*)d_out;

    size_t off = 0;
    auto take = [&](size_t bytes) -> void* {
        void* p = (char*)d_ws + off;
        off += (bytes + 255) & ~(size_t)255;
        return p;
    };
    ushort_t* Fs    = (ushort_t*)take((size_t)NN * HE_DIM * 2);       // 16.8 MB
    ushort_t* Es    = (ushort_t*)take((size_t)MM * ST_DIM * 2);       // 2.1 MB
    ushort_t* Whes  = (ushort_t*)take((size_t)D_OUT * HE_DIM * 2);
    ushort_t* Wsts  = (ushort_t*)take((size_t)D_OUT * ST_DIM * 2);
    float* Xw_he    = (float*)take((size_t)NN * D_OUT * 4);           // 8 MB
    float* Xw_st    = (float*)take((size_t)MM * D_OUT * 4);           // 2 MB
    float* rnF      = (float*)take((size_t)NN * 4);
    float* rnE      = (float*)take((size_t)MM * 4);
    int*   mask     = (int*)  take((size_t)VV * MM * 4);
    int*   maskcnt  = (int*)  take((size_t)VV * 4);
    ushort_t* he_sim = (ushort_t*)take((size_t)VV * PP * PP * 2);     // 16 MB (f16)
    ushort_t* st_sim = (ushort_t*)take((size_t)MM * MM * 2);          // 8 MB (f16)
    int*   he_idx   = (int*)  take((size_t)NN * K_HG * 4);
    int*   st_idx   = (int*)  take((size_t)VV * MM * K_HG * 4);
    // zero-init region (zeroed inside prep): counts + cursors + z accumulators
    size_t zero_beg = off;
    int*   he_cnt   = (int*)  take((size_t)NN * 4);
    int*   st_cnt   = (int*)  take((size_t)VV * MM * 4);
    int*   he_cur   = (int*)  take((size_t)NN * 4);
    int*   st_cur   = (int*)  take((size_t)VV * MM * 4);
    float* zacc_he  = (float*)take((size_t)VV * D_OUT * 4);
    float* zacc_st  = (float*)take((size_t)VV * D_OUT * 4);
    size_t zero_end = off;
    int*   he_inv   = (int*)  take((size_t)NN * DEG_CAP * 4);         // 3 MB
    int*   st_inv   = (int*)  take((size_t)VV * MM * DEG_CAP * 4);    // 6 MB
    ushort_t* he_ev = (ushort_t*)take((size_t)NN * D_OUT * 2);        // 4 MB (bf16)
    ushort_t* st_ev = (ushort_t*)take((size_t)VV * MM * D_OUT * 2);   // 8 MB (bf16)

    int nZeroInts = (int)((zero_end - zero_beg) / 4);

    // bf16 cast + row norms + centroids/mask + zeroing (one launch)
    prep_kernel<<<NPREP + VV, 256, 0, stream>>>(F, E, W_he, W_st, T, S,
                                                Fs, Es, Whes, Wsts, rnF, rnE,
                                                mask, maskcnt,
                                                (int*)((char*)d_ws + zero_beg), nZeroInts);

    // all four GEMMs in one grouped launch (single pass each, [rows][K] bufs)
    gemm_grouped<<<NB_ALL, 256, 0, stream>>>(Fs, Es, Whes, Wsts,
                                             he_sim, st_sim, Xw_he, Xw_st,
                                             rnF, rnE);

    // top-5 + degree counts (packed integer keys, 4 waves/block)
    topk_kernel<<<(NN + VV * MM) / 4, 256, 0, stream>>>(he_sim, st_sim, mask,
                                                        he_idx, st_idx, he_cnt, st_cnt);
    // per-edge values (bf16) + capacity-based inverse fill
    edge_kernel<<<NN + VV * MM, 256, 0, stream>>>(he_idx, st_idx, Xw_he, Xw_st,
                                                  he_cnt, st_cnt,
                                                  he_cur, st_cur, he_inv, st_inv,
                                                  he_ev, st_ev);
    // gather + gelu + atomic pool directly into z accumulators
    pool_gather_kernel<<<VV * HE_NCH + VV * ST_NCH, 256, 0, stream>>>(
        he_ev, st_ev, he_cnt, st_cnt, he_inv, st_inv,
        mask, zacc_he, zacc_st);
    // divide + loss
    final_kernel<<<1, 64, 0, stream>>>(zacc_he, zacc_st, maskcnt, out);
}

// Round 24
// 125.755 us; speedup vs baseline: 1.3027x; 1.0071x over previous
//
#include <hip/hip_runtime.h>
#include <hip/hip_bf16.h>
#include <hip/hip_fp16.h>
#include <math.h>

// ---------------- problem constants ----------------
#define NN      8192
#define VV      8
#define PP      1024      // N / V
#define MM      2048
#define HE_DIM  1024
#define ST_DIM  512
#define D_OUT   256
#define K_HG    5
#define RADIUS  150.0f
#define TEMP    0.07f
#define EPSF    1e-12f

#define POOL_CHUNK 4
#define HE_NCH  (PP / POOL_CHUNK)   // 256
#define ST_NCH  (MM / POOL_CHUNK)   // 512
#define DEG_CAP 96                  // max node in-degree (KNN in-degree max ~20)

// grouped-GEMM block ranges
#define HE_TRI   36                 // 8x8 upper triangle
#define ST_TRI   136                // 16x16 upper triangle
#define NB_HE    (VV * HE_TRI)      // 288
#define NB_ST    ST_TRI             // 136
#define NB_PH    ((NN / 128) * (D_OUT / 128))   // 128
#define NB_PS    ((MM / 128) * (D_OUT / 128))   // 32
#define NB_ALL   (NB_HE + NB_ST + NB_PH + NB_PS) // 584 = 8 * 73

#define NPREP   (NN + MM + 2 * D_OUT)   // rows handled by prep; +VV extra blocks

typedef __bf16 bf16x8 __attribute__((ext_vector_type(8)));
typedef float  f32x4  __attribute__((ext_vector_type(4)));
typedef unsigned short ushort_t;

typedef __attribute__((address_space(1))) void gvoid;
typedef __attribute__((address_space(3))) void svoid;
#define GLOAD16(g, l) __builtin_amdgcn_global_load_lds((gvoid*)(g), (svoid*)(l), 16, 0, 0)
#define FENCE() asm volatile("" ::: "memory")

__device__ __forceinline__ ushort_t f2bf(float x) {
    unsigned int b = __float_as_uint(x);
    return (ushort_t)((b + 0x7fffu + ((b >> 16) & 1u)) >> 16);   // RNE
}
__device__ __forceinline__ float bf2f(ushort_t h) {
    return __uint_as_float(((unsigned int)h) << 16);
}
__device__ __forceinline__ ushort_t f2h(float x) {
    return __half_as_ushort(__float2half_rn(x));
}

// ---------------- fused: bf16 cast + rownorm + (centers/mask/zero in tail blocks) ----------------
__global__ __launch_bounds__(256) void prep_kernel(
    const float* __restrict__ F, const float* __restrict__ E,
    const float* __restrict__ Whe, const float* __restrict__ Wst,
    const float* __restrict__ T, const float* __restrict__ S,
    ushort_t* __restrict__ Fs, ushort_t* __restrict__ Es,
    ushort_t* __restrict__ Whes, ushort_t* __restrict__ Wsts,
    float* __restrict__ rnF, float* __restrict__ rnE,
    int* __restrict__ mask, int* __restrict__ maskcnt,
    int* __restrict__ zeroPtr, int nZeroInts)
{
    int b = blockIdx.x;
    if (b >= NPREP) {
        int v = b - NPREP;
        int per = (nZeroInts + VV - 1) / VV;
        for (int i = threadIdx.x; i < per; i += 256) {
            int idx = v * per + i;
            if (idx < nZeroInts) zeroPtr[idx] = 0;
        }
        float sx = 0.0f, sy = 0.0f;
        for (int i = threadIdx.x; i < PP; i += 256) {
            sx += T[(long)(v * PP + i) * 2 + 0];
            sy += T[(long)(v * PP + i) * 2 + 1];
        }
        __shared__ float rx[256], ry[256];
        __shared__ int   rc[256];
        rx[threadIdx.x] = sx; ry[threadIdx.x] = sy; __syncthreads();
        for (int o = 128; o > 0; o >>= 1) {
            if (threadIdx.x < o) { rx[threadIdx.x] += rx[threadIdx.x + o]; ry[threadIdx.x] += ry[threadIdx.x + o]; }
            __syncthreads();
        }
        float cx = rx[0] / (float)PP, cy = ry[0] / (float)PP;
        __syncthreads();
        int cnt = 0;
        for (int m = threadIdx.x; m < MM; m += 256) {
            float dx = cx - S[m * 2 + 0];
            float dy = cy - S[m * 2 + 1];
            int in = (sqrtf(dx * dx + dy * dy) < RADIUS) ? 1 : 0;
            mask[v * MM + m] = in;
            cnt += in;
        }
        rc[threadIdx.x] = cnt; __syncthreads();
        for (int o = 128; o > 0; o >>= 1) {
            if (threadIdx.x < o) rc[threadIdx.x] += rc[threadIdx.x + o];
            __syncthreads();
        }
        if (threadIdx.x == 0) maskcnt[v] = rc[0];
        return;
    }
    const float* src; ushort_t* dst; float* rn; int K; long row;
    if (b < NN)                    { src = F;   dst = Fs;   rn = rnF;    K = HE_DIM; row = b; }
    else if (b < NN + MM)          { src = E;   dst = Es;   rn = rnE;    K = ST_DIM; row = b - NN; }
    else if (b < NN + MM + D_OUT)  { src = Whe; dst = Whes; rn = nullptr; K = HE_DIM; row = b - NN - MM; }
    else                           { src = Wst; dst = Wsts; rn = nullptr; K = ST_DIM; row = b - NN - MM - D_OUT; }
    const float4* srow = (const float4*)(src + row * (long)K);
    ushort_t* drow = dst + row * (long)K;
    float s = 0.0f;
    for (int j4 = threadIdx.x; j4 < (K >> 2); j4 += 256) {
        float4 x = srow[j4];
        float xs[4] = {x.x, x.y, x.z, x.w};
        ushort_t hs[4];
        #pragma unroll
        for (int t = 0; t < 4; ++t) {
            hs[t] = f2bf(xs[t]);
            s += xs[t] * xs[t];
        }
        *(ushort4*)(drow + j4 * 4) = make_ushort4(hs[0], hs[1], hs[2], hs[3]);
    }
    if (rn) {
        __shared__ float red[256];
        red[threadIdx.x] = s; __syncthreads();
        for (int o = 128; o > 0; o >>= 1) {
            if (threadIdx.x < o) red[threadIdx.x] += red[threadIdx.x + o];
            __syncthreads();
        }
        if (threadIdx.x == 0) rn[row] = 1.0f / fmaxf(sqrtf(red[0]), EPSF);
    }
}

// ---------------- grouped bf16 MFMA GEMM ----------------
// Single pass, 3-buf {A,B} 16 KB bufs, depth-2 prefetch, counted vmcnt.
// 48 KB LDS -> 3 blocks/CU. Buffers are [rows][K] bf16 (contiguous).
// Sims stored f16; projections stored bf16 (consumed only by edge gather).
__global__ __launch_bounds__(256) void gemm_grouped(
    const ushort_t* __restrict__ Fs, const ushort_t* __restrict__ Es,
    const ushort_t* __restrict__ Whes, const ushort_t* __restrict__ Wsts,
    ushort_t* __restrict__ he_sim, ushort_t* __restrict__ st_sim,
    ushort_t* __restrict__ Xw_he, ushort_t* __restrict__ Xw_st,
    const float* __restrict__ rnF, const float* __restrict__ rnE)
{
    // XCD map: per-xcd order = proj (longest with HE), ST, then HE (own-region tiles).
    int bid = blockIdx.x;
    int xcd = bid & 7, j = bid >> 3;    // j in [0,73); 584 = 8*73 bijective
    int id;
    if (j < 20)      id = NB_HE + (17 + j) * 8 + xcd;    // proj: rest-rows 17..36
    else if (j < 37) id = NB_HE + (j - 20) * 8 + xcd;    // ST:   rest-rows 0..16
    else             id = xcd * HE_TRI + (j - 37);       // HE:   own region

    const ushort_t *A, *B; ushort_t *Ch = nullptr; ushort_t *Cf = nullptr;
    const float *rA = nullptr, *rB = nullptr;
    int K, Nn, bm, bn, sym;
    if (id < NB_HE) {
        int z = id / HE_TRI, t = id - z * HE_TRI;
        int i = 0;
        while (t >= 8 - i) { t -= 8 - i; ++i; }
        bm = i * 128; bn = (i + t) * 128;
        A = B = Fs + (long)z * PP * HE_DIM;
        Ch = he_sim + (long)z * PP * PP;
        rA = rB = rnF + z * PP;
        K = HE_DIM; Nn = PP; sym = 1;
    } else if (id < NB_HE + NB_ST) {
        int t = id - NB_HE;
        int i = 0;
        while (t >= 16 - i) { t -= 16 - i; ++i; }
        bm = i * 128; bn = (i + t) * 128;
        A = B = Es; Ch = st_sim; rA = rB = rnE;
        K = ST_DIM; Nn = MM; sym = 1;
    } else if (id < NB_HE + NB_ST + NB_PH) {
        int t = id - (NB_HE + NB_ST);
        bm = (t >> 1) * 128; bn = (t & 1) * 128;
        A = Fs; B = Whes; Cf = Xw_he;
        K = HE_DIM; Nn = D_OUT; sym = 0;
    } else {
        int t = id - (NB_HE + NB_ST + NB_PH);
        bm = (t >> 1) * 128; bn = (t & 1) * 128;
        A = Es; B = Wsts; Cf = Xw_st;
        K = ST_DIM; Nn = D_OUT; sym = 0;
    }

    __shared__ ushort_t sm[24576];   // 48 KB: 3 bufs x {A 8KB, B 8KB}
    char* const smb = (char*)&sm[0];
    const int tid  = threadIdx.x;
    const int lane = tid & 63, wave = tid >> 6;
    const int wr = wave >> 1, wc = wave & 1;
    const int fr = lane & 15, fg = lane >> 4;

    const long lda = (long)K;
    const int srow = wave * 16 + (lane >> 2);
    const int scol = (((lane & 3) ^ ((srow >> 1) & 3)) * 8);  // pre-swizzled src col

    f32x4 acc[4][4] = {};

    auto roA = [&](int m) { int row = wr * 64 + m * 16 + fr;
                            return row * 64 + ((fg ^ ((row >> 1) & 3)) * 16); };
    auto roB = [&](int n) { int row = wc * 64 + n * 16 + fr;
                            return row * 64 + ((fg ^ ((row >> 1) & 3)) * 16); };

    auto STG = [&](int kk, int b) {
        const ushort_t* ga = A + (long)(bm + srow) * lda + kk + scol;
        const ushort_t* gb = B + (long)(bn + srow) * lda + kk + scol;
        char* AT = smb + b * 16384 + wave * 1024;
        char* BT = AT + 8192;
        GLOAD16(ga, AT); GLOAD16(ga + 64 * lda, AT + 4096);
        GLOAD16(gb, BT); GLOAD16(gb + 64 * lda, BT + 4096);
    };
    STG(0, 0); STG(32, 1);
    int buf = 0;
    for (int kk = 0; kk < K; kk += 32) {
        if (kk + 64 < K) {
            STG(kk + 64, buf == 0 ? 2 : buf - 1);
            asm volatile("s_waitcnt vmcnt(8)" ::: "memory");
        } else if (kk + 32 < K) {
            asm volatile("s_waitcnt vmcnt(4)" ::: "memory");
        } else {
            asm volatile("s_waitcnt vmcnt(0)" ::: "memory");
        }
        FENCE(); __builtin_amdgcn_s_barrier(); FENCE();
        const char* ab = smb + buf * 16384;
        bf16x8 a4[4], b4[4];
        #pragma unroll
        for (int m = 0; m < 4; ++m) a4[m] = *(const bf16x8*)(ab + roA(m));
        #pragma unroll
        for (int n = 0; n < 4; ++n) b4[n] = *(const bf16x8*)(ab + 8192 + roB(n));
        #pragma unroll
        for (int m = 0; m < 4; ++m)
            #pragma unroll
            for (int n = 0; n < 4; ++n)
                acc[m][n] = __builtin_amdgcn_mfma_f32_16x16x32_bf16(a4[m], b4[n], acc[m][n], 0, 0, 0);
        FENCE(); __builtin_amdgcn_s_barrier(); FENCE();
        buf = (buf == 2) ? 0 : buf + 1;
    }

    if (sym) {
        // ---- direct store (f16) ----
        #pragma unroll
        for (int m = 0; m < 4; ++m) {
            #pragma unroll
            for (int r = 0; r < 4; ++r) {
                int row = bm + wr * 64 + m * 16 + fg * 4 + r;
                float ra = rA[row];
                #pragma unroll
                for (int n = 0; n < 4; ++n) {
                    int col = bn + wc * 64 + n * 16 + fr;
                    Ch[(long)row * Nn + col] = f2h(acc[m][n][r] * ra * rB[col]);
                }
            }
        }
        if (bn > bm) {
            // ---- mirror store via LDS transpose (f16 out) ----
            float* tbuf = (float*)smb;
            #pragma unroll
            for (int h = 0; h < 2; ++h) {
                __syncthreads();
                if (wc == h) {
                    #pragma unroll
                    for (int m = 0; m < 4; ++m)
                        #pragma unroll
                        for (int r = 0; r < 4; ++r) {
                            int row = wr * 64 + m * 16 + fg * 4 + r;
                            float ra = rA[bm + row];
                            #pragma unroll
                            for (int n = 0; n < 4; ++n) {
                                int cloc = n * 16 + fr;
                                float rb = rB[bn + h * 64 + cloc];
                                tbuf[cloc * 132 + row] = acc[m][n][r] * ra * rb;
                            }
                        }
                }
                __syncthreads();
                #pragma unroll
                for (int q = 0; q < 8; ++q) {
                    int fi = (q * 256 + tid) * 4;    // 0..8191
                    int rp = fi >> 7;                // transposed row 0..63
                    int cp = fi & 127;               // col 0..127 (step 4)
                    ushort4 val = make_ushort4(
                        f2h(tbuf[rp * 132 + cp]),     f2h(tbuf[rp * 132 + cp + 1]),
                        f2h(tbuf[rp * 132 + cp + 2]), f2h(tbuf[rp * 132 + cp + 3]));
                    *(ushort4*)&Ch[(long)(bn + h * 64 + rp) * Nn + bm + cp] = val;
                }
            }
        }
    } else {
        // ---- direct store (bf16, projections) ----
        #pragma unroll
        for (int m = 0; m < 4; ++m) {
            #pragma unroll
            for (int r = 0; r < 4; ++r) {
                int row = bm + wr * 64 + m * 16 + fg * 4 + r;
                #pragma unroll
                for (int n = 0; n < 4; ++n) {
                    int col = bn + wc * 64 + n * 16 + fr;
                    Cf[(long)row * Nn + col] = f2bf(acc[m][n][r]);
                }
            }
        }
    }
}

// ---------------- merged top-5 per row + degree counts (packed-key, 4 waves/block) ----------------
__global__ __launch_bounds__(256) void topk_kernel(
    const ushort_t* __restrict__ he_sim, const ushort_t* __restrict__ st_sim,
    const int* __restrict__ mask,
    int* __restrict__ he_idx, int* __restrict__ st_idx,
    int* __restrict__ he_cnt, int* __restrict__ st_cnt)
{
    int gb = blockIdx.x * 4 + (threadIdx.x >> 6);
    int lane = threadIdx.x & 63;
    unsigned k0 = 0, k1 = 0, k2 = 0, k3 = 0, k4 = 0;
    int* outIdx; int* cntp;

    auto skey = [](unsigned h) -> unsigned {
        unsigned s = h >> 15;
        return h ^ (((0u - s) | 0x8000u) & 0xFFFFu);
    };
    auto insk = [&](unsigned key) {
        bool c0 = key > k0, c1 = key > k1, c2 = key > k2, c3 = key > k3, c4 = key > k4;
        k4 = c4 ? (c3 ? k3 : key) : k4;
        k3 = c3 ? (c2 ? k2 : key) : k3;
        k2 = c2 ? (c1 ? k1 : key) : k2;
        k1 = c1 ? (c0 ? k0 : key) : k1;
        k0 = c0 ? key : k0;
    };

    if (gb < NN) {
        int z = gb >> 10;
        const uint4* row8 = (const uint4*)(he_sim + (long)z * PP * PP + (long)(gb & (PP - 1)) * PP);
        outIdx = he_idx + (long)gb * K_HG;
        cntp = he_cnt + z * PP;
        #pragma unroll
        for (int it = 0; it < (PP / 8) / 64; ++it) {      // 2 iters
            int j8 = it * 64 + lane;
            uint4 u = row8[j8];
            unsigned inv = 0xFFFFu - (unsigned)(j8 * 8);
            insk((skey(u.x & 0xFFFFu) << 16) | inv);
            insk((skey(u.x >> 16)     << 16) | (inv - 1));
            insk((skey(u.y & 0xFFFFu) << 16) | (inv - 2));
            insk((skey(u.y >> 16)     << 16) | (inv - 3));
            insk((skey(u.z & 0xFFFFu) << 16) | (inv - 4));
            insk((skey(u.z >> 16)     << 16) | (inv - 5));
            insk((skey(u.w & 0xFFFFu) << 16) | (inv - 6));
            insk((skey(u.w >> 16)     << 16) | (inv - 7));
        }
    } else {
        int g2 = gb - NN;
        int z = g2 >> 11, e = g2 & (MM - 1);
        const int* mk = mask + (long)z * MM;
        outIdx = st_idx + (long)g2 * K_HG;
        cntp = st_cnt + z * MM;
        if (mk[e] == 0) {
            if (lane == 0) {
                #pragma unroll
                for (int r = 0; r < K_HG; ++r) outIdx[r] = -1;
            }
            return;
        }
        const uint4* row8 = (const uint4*)(st_sim + (long)e * MM);
        const int4*  mk4  = (const int4*)mk;
        #pragma unroll
        for (int it = 0; it < (MM / 8) / 64; ++it) {      // 4 iters
            int j8 = it * 64 + lane;
            uint4 u = row8[j8];
            int4 ma = mk4[2 * j8], mb = mk4[2 * j8 + 1];
            unsigned inv = 0xFFFFu - (unsigned)(j8 * 8);
            insk(ma.x ? ((skey(u.x & 0xFFFFu) << 16) | inv)       : 0u);
            insk(ma.y ? ((skey(u.x >> 16)     << 16) | (inv - 1)) : 0u);
            insk(ma.z ? ((skey(u.y & 0xFFFFu) << 16) | (inv - 2)) : 0u);
            insk(ma.w ? ((skey(u.y >> 16)     << 16) | (inv - 3)) : 0u);
            insk(mb.x ? ((skey(u.z & 0xFFFFu) << 16) | (inv - 4)) : 0u);
            insk(mb.y ? ((skey(u.z >> 16)     << 16) | (inv - 5)) : 0u);
            insk(mb.z ? ((skey(u.w & 0xFFFFu) << 16) | (inv - 6)) : 0u);
            insk(mb.w ? ((skey(u.w >> 16)     << 16) | (inv - 7)) : 0u);
        }
    }

    // 5 rounds of wave max merge (keys unique -> exact pop)
    #pragma unroll
    for (int r = 0; r < K_HG; ++r) {
        unsigned bk = k0;
        for (int o = 32; o > 0; o >>= 1) {
            unsigned ok = (unsigned)__shfl_xor((int)bk, o, 64);
            bk = ok > bk ? ok : bk;
        }
        if (lane == 0) {
            int bi = (int)(0xFFFFu - (bk & 0xFFFFu));
            outIdx[r] = bi;
            atomicAdd(&cntp[bi], 1);
        }
        if (k0 == bk) {
            k0 = k1; k1 = k2; k2 = k3; k3 = k4; k4 = 0;
        }
    }
}

// ---------------- merged per-edge value (bf16 out) + capacity-CSR fill ----------------
__global__ __launch_bounds__(256) void edge_kernel(
    const int* __restrict__ he_idx, const int* __restrict__ st_idx,
    const ushort_t* __restrict__ Xw_he, const ushort_t* __restrict__ Xw_st,
    const int* __restrict__ he_cnt, const int* __restrict__ st_cnt,
    int* __restrict__ he_cur, int* __restrict__ st_cur,
    int* __restrict__ he_inv, int* __restrict__ st_inv,
    ushort_t* __restrict__ he_ev, ushort_t* __restrict__ st_ev)
{
    int b = blockIdx.x;
    const int *idx, *cnt; const ushort_t* Xw;
    int *cur, *inv; ushort_t* ev;
    int ge, gbase, rowsPerZ; long xwBase;
    if (b < NN) {
        ge = b; int z = ge >> 10;
        idx = he_idx; Xw = Xw_he; cnt = he_cnt;
        cur = he_cur; inv = he_inv; ev = he_ev;
        rowsPerZ = PP; gbase = z * PP; xwBase = (long)z * PP;
    } else {
        ge = b - NN; int z = ge >> 11;
        idx = st_idx; Xw = Xw_st; cnt = st_cnt;
        cur = st_cur; inv = st_inv; ev = st_ev;
        rowsPerZ = MM; gbase = z * MM; xwBase = 0;
    }
    int mm[K_HG];
    #pragma unroll
    for (int k = 0; k < K_HG; ++k) mm[k] = idx[(long)ge * K_HG + k];
    if (mm[0] < 0) return;   // masked-out ST edge
    int d = threadIdx.x;
    float val = 0.0f;
    #pragma unroll
    for (int k = 0; k < K_HG; ++k) {
        int m = mm[k];
        if (m < 0 || m >= rowsPerZ) continue;
        float w = rsqrtf(fmaxf((float)cnt[gbase + m], EPSF));
        val += w * bf2f(Xw[(xwBase + m) * D_OUT + d]);
    }
    ev[(long)ge * D_OUT + d] = f2bf(val * (1.0f / (float)K_HG));
    if (d < K_HG) {
        int m = mm[d];
        if (m >= 0 && m < rowsPerZ) {
            int g = gbase + m;
            int pos = atomicAdd(&cur[g], 1);
            if (pos < DEG_CAP) inv[(long)g * DEG_CAP + pos] = ge;
        }
    }
}

// ---------------- node gather + Dv^-1/2 + GELU + atomic pool into z ----------------
__global__ __launch_bounds__(256) void pool_gather_kernel(
    const ushort_t* __restrict__ he_ev, const ushort_t* __restrict__ st_ev,
    const int* __restrict__ he_cnt, const int* __restrict__ st_cnt,
    const int* __restrict__ he_inv, const int* __restrict__ st_inv,
    const int* __restrict__ mask,
    float* __restrict__ zacc_he, float* __restrict__ zacc_st)
{
    int blk = blockIdx.x;
    const ushort_t* ev; const int *cnt, *inv, *msk = nullptr;
    float* zt; int gbase, i0;
    if (blk < VV * HE_NCH) {
        int z = blk / HE_NCH, c = blk % HE_NCH;
        ev = he_ev; cnt = he_cnt; inv = he_inv;
        zt = zacc_he + z * D_OUT;
        gbase = z * PP; i0 = c * POOL_CHUNK;
    } else {
        int b2 = blk - VV * HE_NCH;
        int z = b2 / ST_NCH, c = b2 % ST_NCH;
        ev = st_ev; cnt = st_cnt; inv = st_inv;
        msk = mask;
        zt = zacc_st + z * D_OUT;
        gbase = z * MM; i0 = c * POOL_CHUNK;
    }
    int d = threadIdx.x;
    float s = 0.0f;
    bool any = false;
    #pragma unroll
    for (int i = 0; i < POOL_CHUNK; ++i) {
        int g = gbase + i0 + i;
        if (msk && msk[g] == 0) continue;
        any = true;
        int cn = cnt[g];
        const int* ip = inv + (long)g * DEG_CAP;
        float a = 0.0f;
        for (int e = 0; e < cn; ++e)
            a += bf2f(ev[(long)ip[e] * D_OUT + d]);
        float w = rsqrtf(fmaxf((float)cn, EPSF));
        float x = w * a;
        s += 0.5f * x * (1.0f + erff(x * 0.70710678118654752f));   // exact GELU
    }
    if (any || !msk) atomicAdd(&zt[d], s);
}

// ---------------- final: divide + l2norm + contrastive loss ----------------
__global__ __launch_bounds__(64) void final_kernel(const float* __restrict__ zacc_he,
                                                   const float* __restrict__ zacc_st,
                                                   const int* __restrict__ maskcnt,
                                                   float* __restrict__ out) {
    __shared__ float he[VV][D_OUT];
    __shared__ float st[VV][D_OUT];
    __shared__ float lg[VV][VV];
    __shared__ float rn_he[VV], rn_st[VV];
    int t = threadIdx.x;
    for (int i = t; i < VV * D_OUT; i += 64) {
        int v = i >> 8;
        he[v][i & 255] = zacc_he[i] / (float)PP;
        st[v][i & 255] = zacc_st[i] / (float)maskcnt[v];
    }
    __syncthreads();
    if (t < VV) {
        float s = 0.0f;
        for (int d2 = 0; d2 < D_OUT; ++d2) s += he[t][d2] * he[t][d2];
        rn_he[t] = 1.0f / fmaxf(sqrtf(s), EPSF);
    } else if (t < 2 * VV) {
        int v = t - VV; float s = 0.0f;
        for (int d2 = 0; d2 < D_OUT; ++d2) s += st[v][d2] * st[v][d2];
        rn_st[v] = 1.0f / fmaxf(sqrtf(s), EPSF);
    }
    __syncthreads();
    int v = t >> 3, w2 = t & 7;
    float dot = 0.0f;
    for (int d2 = 0; d2 < D_OUT; ++d2) dot += he[v][d2] * st[w2][d2];
    lg[v][w2] = dot * rn_he[v] * rn_st[w2] / TEMP;
    __syncthreads();
    if (t == 0) {
        float l1 = 0.0f, l2 = 0.0f;
        for (int i = 0; i < VV; ++i) {
            float mx = -1e30f;
            for (int jj = 0; jj < VV; ++jj) mx = fmaxf(mx, lg[i][jj]);
            float se = 0.0f;
            for (int jj = 0; jj < VV; ++jj) se += expf(lg[i][jj] - mx);
            l1 += lg[i][i] - (mx + logf(se));
            float mx2 = -1e30f;
            for (int jj = 0; jj < VV; ++jj) mx2 = fmaxf(mx2, lg[jj][i]);
            float se2 = 0.0f;
            for (int jj = 0; jj < VV; ++jj) se2 += expf(lg[jj][i] - mx2);
            l2 += lg[i][i] - (mx2 + logf(se2));
        }
        out[0] = 0.5f * (-(l1 / (float)VV) - (l2 / (float)VV));
    }
}

// ---------------- launch ----------------
extern "C" void kernel_launch(void* const* d_in, const int* in_sizes, int n_in,
                              void* d_out, int out_size, void* d_ws, size_t ws_size,
                              hipStream_t stream) {
    const float* F    = (const float*)d_in[0];
    const float* T    = (const float*)d_in[1];
    const float* E    = (const float*)d_in[3];
    const float* S    = (const float*)d_in[4];
    const float* W_he = (const float*)d_in[5];
    const float* W_st = (const float*)d_in[6];
    float* out = (float*)d_out;

    size_t off = 0;
    auto take = [&](size_t bytes) -> void* {
        void* p = (char*)d_ws + off;
        off += (bytes + 255) & ~(size_t)255;
        return p;
    };
    ushort_t* Fs    = (ushort_t*)take((size_t)NN * HE_DIM * 2);       // 16.8 MB
    ushort_t* Es    = (ushort_t*)take((size_t)MM * ST_DIM * 2);       // 2.1 MB
    ushort_t* Whes  = (ushort_t*)take((size_t)D_OUT * HE_DIM * 2);
    ushort_t* Wsts  = (ushort_t*)take((size_t)D_OUT * ST_DIM * 2);
    ushort_t* Xw_he = (ushort_t*)take((size_t)NN * D_OUT * 2);        // 4 MB (bf16)
    ushort_t* Xw_st = (ushort_t*)take((size_t)MM * D_OUT * 2);        // 1 MB (bf16)
    float* rnF      = (float*)take((size_t)NN * 4);
    float* rnE      = (float*)take((size_t)MM * 4);
    int*   mask     = (int*)  take((size_t)VV * MM * 4);
    int*   maskcnt  = (int*)  take((size_t)VV * 4);
    ushort_t* he_sim = (ushort_t*)take((size_t)VV * PP * PP * 2);     // 16 MB (f16)
    ushort_t* st_sim = (ushort_t*)take((size_t)MM * MM * 2);          // 8 MB (f16)
    int*   he_idx   = (int*)  take((size_t)NN * K_HG * 4);
    int*   st_idx   = (int*)  take((size_t)VV * MM * K_HG * 4);
    // zero-init region (zeroed inside prep): counts + cursors + z accumulators
    size_t zero_beg = off;
    int*   he_cnt   = (int*)  take((size_t)NN * 4);
    int*   st_cnt   = (int*)  take((size_t)VV * MM * 4);
    int*   he_cur   = (int*)  take((size_t)NN * 4);
    int*   st_cur   = (int*)  take((size_t)VV * MM * 4);
    float* zacc_he  = (float*)take((size_t)VV * D_OUT * 4);
    float* zacc_st  = (float*)take((size_t)VV * D_OUT * 4);
    size_t zero_end = off;
    int*   he_inv   = (int*)  take((size_t)NN * DEG_CAP * 4);         // 3 MB
    int*   st_inv   = (int*)  take((size_t)VV * MM * DEG_CAP * 4);    // 6 MB
    ushort_t* he_ev = (ushort_t*)take((size_t)NN * D_OUT * 2);        // 4 MB (bf16)
    ushort_t* st_ev = (ushort_t*)take((size_t)VV * MM * D_OUT * 2);   // 8 MB (bf16)

    int nZeroInts = (int)((zero_end - zero_beg) / 4);

    // bf16 cast + row norms + centroids/mask + zeroing (one launch)
    prep_kernel<<<NPREP + VV, 256, 0, stream>>>(F, E, W_he, W_st, T, S,
                                                Fs, Es, Whes, Wsts, rnF, rnE,
                                                mask, maskcnt,
                                                (int*)((char*)d_ws + zero_beg), nZeroInts);

    // all four GEMMs in one grouped launch (single pass each, [rows][K] bufs)
    gemm_grouped<<<NB_ALL, 256, 0, stream>>>(Fs, Es, Whes, Wsts,
                                             he_sim, st_sim, Xw_he, Xw_st,
                                             rnF, rnE);

    // top-5 + degree counts (packed integer keys, 4 waves/block)
    topk_kernel<<<(NN + VV * MM) / 4, 256, 0, stream>>>(he_sim, st_sim, mask,
                                                        he_idx, st_idx, he_cnt, st_cnt);
    // per-edge values (bf16) + capacity-based inverse fill
    edge_kernel<<<NN + VV * MM, 256, 0, stream>>>(he_idx, st_idx, Xw_he, Xw_st,
                                                  he_cnt, st_cnt,
                                                  he_cur, st_cur, he_inv, st_inv,
                                                  he_ev, st_ev);
    // gather + gelu + atomic pool directly into z accumulators
    pool_gather_kernel<<<VV * HE_NCH + VV * ST_NCH, 256, 0, stream>>>(
        he_ev, st_ev, he_cnt, st_cnt, he_inv, st_inv,
        mask, zacc_he, zacc_st);
    // divide + loss
    final_kernel<<<1, 64, 0, stream>>>(zacc_he, zacc_st, maskcnt, out);
}